// Round 1
// baseline (9694.698 us; speedup 1.0000x reference)
//
#include <hip/hip_runtime.h>

// GIN encoder w/ virtual node, 3 layers, H=128. Full f32 implementation.
// N=100000 nodes, E=1.6M edges, G=512 graphs (fixed by setup_inputs).

#define HDIM 128
#define H2DIM 256
#define GNUM 512
#define BN_EPS 1e-5f

// ---------------- elementwise / init ----------------

__global__ __launch_bounds__(256) void k_init_vf(const float* __restrict__ emb,
                                                 float* __restrict__ vf) {
  int idx = blockIdx.x * 256 + threadIdx.x;
  if (idx < GNUM * HDIM) vf[idx] = emb[idx & (HDIM - 1)];
}

// h = feats (+ vf[batch]); z = h   (z may alias feats: per-thread read-then-write)
__global__ __launch_bounds__(256) void k_h_init(const float* __restrict__ feats,
                                                const float* __restrict__ vf,
                                                const int* __restrict__ batch,
                                                float* __restrict__ h,
                                                float* __restrict__ z,
                                                int N, int useVf) {
  int idx = blockIdx.x * 256 + threadIdx.x;
  int total = N * (HDIM / 4);
  if (idx >= total) return;
  int n = idx >> 5;          // HDIM/4 == 32
  int c4 = idx & 31;
  float4 v = ((const float4*)feats)[idx];
  if (useVf) {
    int g = batch[n];
    float4 w = ((const float4*)(vf + (size_t)g * HDIM))[c4];
    v.x += w.x; v.y += w.y; v.z += w.z; v.w += w.w;
  }
  ((float4*)h)[idx] = v;
  ((float4*)z)[idx] = v;
}

// z[dst] += h[src] over all edges. 32 lanes per edge, float4 each.
__global__ __launch_bounds__(256) void k_scatter(const float* __restrict__ h,
                                                 const int* __restrict__ ei,
                                                 float* __restrict__ z, int E) {
  long long idx = (long long)blockIdx.x * 256 + threadIdx.x;
  if (idx >= (long long)E * 32) return;
  int e = (int)(idx >> 5);
  int c4 = (int)(idx & 31);
  int s = ei[e];       // edge_index[0][e]
  int d = ei[E + e];   // edge_index[1][e]
  float4 v = ((const float4*)(h + (size_t)s * HDIM))[c4];
  float* zp = z + (size_t)d * HDIM + c4 * 4;
  atomicAdd(zp + 0, v.x);
  atomicAdd(zp + 1, v.y);
  atomicAdd(zp + 2, v.z);
  atomicAdd(zp + 3, v.w);
}

// ---------------- GEMM: C = act(A) @ B + bias ----------------
// A [M,K] row-major; optional per-k BN+ReLU transform on A elements.
// B [K,Nc] row-major. 64x64 tile, BK=16, 256 threads, 4x4 microtile.
__global__ __launch_bounds__(256) void k_gemm(const float* __restrict__ A,
                                              const float* __restrict__ B,
                                              const float* __restrict__ bias,
                                              const float* __restrict__ kscale,
                                              const float* __restrict__ kshift,
                                              float* __restrict__ C,
                                              int M, int K, int Nc) {
  __shared__ float As[16][65];
  __shared__ float Bs[16][65];
  int tid = threadIdx.x;
  int bm = blockIdx.x * 64;
  int bn = blockIdx.y * 64;
  int trow = (tid >> 4) << 2;
  int tcol = (tid & 15) << 2;
  float acc[4][4];
#pragma unroll
  for (int r = 0; r < 4; ++r)
#pragma unroll
    for (int c = 0; c < 4; ++c) acc[r][c] = 0.f;

  int arow = tid >> 2;          // 0..63
  int ak = (tid & 3) << 2;      // 0,4,8,12
  int bt4 = tid << 2;
  int bk = bt4 >> 6;            // 0..15
  int bcol = bt4 & 63;

  for (int kt = 0; kt < K; kt += 16) {
    float4 av = make_float4(0.f, 0.f, 0.f, 0.f);
    int grow = bm + arow;
    if (grow < M) av = *(const float4*)(A + (size_t)grow * K + kt + ak);
    if (kscale) {
      int k0 = kt + ak;
      av.x = fmaxf(fmaf(av.x, kscale[k0 + 0], kshift[k0 + 0]), 0.f);
      av.y = fmaxf(fmaf(av.y, kscale[k0 + 1], kshift[k0 + 1]), 0.f);
      av.z = fmaxf(fmaf(av.z, kscale[k0 + 2], kshift[k0 + 2]), 0.f);
      av.w = fmaxf(fmaf(av.w, kscale[k0 + 3], kshift[k0 + 3]), 0.f);
    }
    float4 bv = *(const float4*)(B + (size_t)(kt + bk) * Nc + bn + bcol);
    __syncthreads();
    As[ak + 0][arow] = av.x;
    As[ak + 1][arow] = av.y;
    As[ak + 2][arow] = av.z;
    As[ak + 3][arow] = av.w;
    Bs[bk][bcol + 0] = bv.x;
    Bs[bk][bcol + 1] = bv.y;
    Bs[bk][bcol + 2] = bv.z;
    Bs[bk][bcol + 3] = bv.w;
    __syncthreads();
#pragma unroll
    for (int k = 0; k < 16; ++k) {
      float a0 = As[k][trow + 0], a1 = As[k][trow + 1];
      float a2 = As[k][trow + 2], a3 = As[k][trow + 3];
      float b0 = Bs[k][tcol + 0], b1 = Bs[k][tcol + 1];
      float b2 = Bs[k][tcol + 2], b3 = Bs[k][tcol + 3];
      acc[0][0] = fmaf(a0, b0, acc[0][0]); acc[0][1] = fmaf(a0, b1, acc[0][1]);
      acc[0][2] = fmaf(a0, b2, acc[0][2]); acc[0][3] = fmaf(a0, b3, acc[0][3]);
      acc[1][0] = fmaf(a1, b0, acc[1][0]); acc[1][1] = fmaf(a1, b1, acc[1][1]);
      acc[1][2] = fmaf(a1, b2, acc[1][2]); acc[1][3] = fmaf(a1, b3, acc[1][3]);
      acc[2][0] = fmaf(a2, b0, acc[2][0]); acc[2][1] = fmaf(a2, b1, acc[2][1]);
      acc[2][2] = fmaf(a2, b2, acc[2][2]); acc[2][3] = fmaf(a2, b3, acc[2][3]);
      acc[3][0] = fmaf(a3, b0, acc[3][0]); acc[3][1] = fmaf(a3, b1, acc[3][1]);
      acc[3][2] = fmaf(a3, b2, acc[3][2]); acc[3][3] = fmaf(a3, b3, acc[3][3]);
    }
  }
#pragma unroll
  for (int r = 0; r < 4; ++r) {
    int grow = bm + trow + r;
    if (grow < M) {
      float4 o;
      o.x = acc[r][0] + bias[bn + tcol + 0];
      o.y = acc[r][1] + bias[bn + tcol + 1];
      o.z = acc[r][2] + bias[bn + tcol + 2];
      o.w = acc[r][3] + bias[bn + tcol + 3];
      *(float4*)(C + (size_t)grow * Nc + bn + tcol) = o;
    }
  }
}

// ---------------- BN stats / finalize / apply ----------------

__global__ void k_colstats(const float* __restrict__ Y, int M, int C, int stripe,
                           float* __restrict__ sum, float* __restrict__ sumsq) {
  int c = threadIdx.x;             // blockDim.x == C
  int r0 = blockIdx.x * stripe;
  int r1 = min(r0 + stripe, M);
  float s = 0.f, ss = 0.f;
  for (int r = r0; r < r1; ++r) {
    float v = Y[(size_t)r * C + c];
    s += v; ss += v * v;
  }
  atomicAdd(&sum[c], s);
  atomicAdd(&sumsq[c], ss);
}

__global__ void k_bnfin(const float* __restrict__ sum, const float* __restrict__ sumsq,
                        const float* __restrict__ g, const float* __restrict__ b,
                        float* __restrict__ scale, float* __restrict__ shift,
                        int C, float invM) {
  int c = threadIdx.x;
  if (c >= C) return;
  float mean = sum[c] * invM;
  float var = sumsq[c] * invM - mean * mean;
  float inv = rsqrtf(var + BN_EPS);
  float sc = g[c] * inv;
  scale[c] = sc;
  shift[c] = fmaf(-mean, sc, b[c]);
}

__global__ __launch_bounds__(256) void k_bnapply(const float* __restrict__ Y,
                                                 const float* __restrict__ scale,
                                                 const float* __restrict__ shift,
                                                 float* __restrict__ out,
                                                 long long total4, int Cq, int relu) {
  long long idx = (long long)blockIdx.x * 256 + threadIdx.x;
  if (idx >= total4) return;
  int c = (int)(idx % Cq) * 4;
  float4 v = ((const float4*)Y)[idx];
  v.x = fmaf(v.x, scale[c + 0], shift[c + 0]);
  v.y = fmaf(v.y, scale[c + 1], shift[c + 1]);
  v.z = fmaf(v.z, scale[c + 2], shift[c + 2]);
  v.w = fmaf(v.w, scale[c + 3], shift[c + 3]);
  if (relu) {
    v.x = fmaxf(v.x, 0.f); v.y = fmaxf(v.y, 0.f);
    v.z = fmaxf(v.z, 0.f); v.w = fmaxf(v.w, 0.f);
  }
  ((float4*)out)[idx] = v;
}

// ---------------- pooling / readout / small ops ----------------

__global__ __launch_bounds__(256) void k_pool(const float* __restrict__ X,
                                              const int* __restrict__ batch,
                                              float* __restrict__ pooled, int N) {
  int idx = blockIdx.x * 256 + threadIdx.x;
  if (idx >= N * HDIM) return;
  int n = idx >> 7;        // /128
  int c = idx & 127;
  atomicAdd(&pooled[(size_t)batch[n] * HDIM + c], X[idx]);
}

__global__ __launch_bounds__(256) void k_counts(const int* __restrict__ batch,
                                                float* __restrict__ counts, int N) {
  int n = blockIdx.x * 256 + threadIdx.x;
  if (n < N) atomicAdd(&counts[batch[n]], 1.0f);
}

__global__ __launch_bounds__(256) void k_add(const float* __restrict__ a,
                                             const float* __restrict__ b,
                                             float* __restrict__ o, int n) {
  int idx = blockIdx.x * 256 + threadIdx.x;
  if (idx < n) o[idx] = a[idx] + b[idx];
}

__global__ __launch_bounds__(256) void k_readout(const float* __restrict__ pooled,
                                                 const float* __restrict__ counts,
                                                 float* __restrict__ out, int n) {
  int idx = blockIdx.x * 256 + threadIdx.x;
  if (idx >= n) return;
  int g = idx >> 7;
  out[idx] = pooled[idx] / fmaxf(counts[g], 1.0f);
}

// ---------------- launch ----------------

extern "C" void kernel_launch(void* const* d_in, const int* in_sizes, int n_in,
                              void* d_out, int out_size, void* d_ws, size_t ws_size,
                              hipStream_t stream) {
  const float* x       = (const float*)d_in[0];
  const int*   ei      = (const int*)d_in[1];
  const int*   batch   = (const int*)d_in[2];
  const float* conv_w1 = (const float*)d_in[4];
  const float* conv_b1 = (const float*)d_in[5];
  const float* conv_bng = (const float*)d_in[6];
  const float* conv_bnb = (const float*)d_in[7];
  const float* conv_w2 = (const float*)d_in[8];
  const float* conv_b2 = (const float*)d_in[9];
  const float* bn_g    = (const float*)d_in[10];
  const float* bn_b    = (const float*)d_in[11];
  const float* vn_emb  = (const float*)d_in[12];
  const float* vw1     = (const float*)d_in[13];
  const float* vb1     = (const float*)d_in[14];
  const float* vbn1g   = (const float*)d_in[15];
  const float* vbn1b   = (const float*)d_in[16];
  const float* vw2     = (const float*)d_in[17];
  const float* vb2     = (const float*)d_in[18];
  const float* vbn2g   = (const float*)d_in[19];
  const float* vbn2b   = (const float*)d_in[20];

  const int N = in_sizes[2];
  const int E = in_sizes[1] / 2;
  const int L = 3;

  const size_t NH  = (size_t)N * HDIM;
  const size_t NH2 = (size_t)N * H2DIM;

  // workspace layout (~155 MB): h | y1 | stats | vf | pooled | vin | v1 | counts
  float* h      = (float*)d_ws;
  float* y1     = h + NH;
  float* sum1   = y1 + NH2;
  float* ss1    = sum1 + H2DIM;
  float* sum2   = ss1 + H2DIM;
  float* ss2    = sum2 + HDIM;
  float* scale1 = ss2 + HDIM;
  float* shift1 = scale1 + H2DIM;
  float* scale2 = shift1 + H2DIM;
  float* shift2 = scale2 + HDIM;
  float* vf     = shift2 + HDIM;
  float* pooled = vf + (size_t)GNUM * HDIM;
  float* vin    = pooled + (size_t)GNUM * HDIM;
  float* v1     = vin + (size_t)GNUM * HDIM;
  float* counts = v1 + (size_t)GNUM * H2DIM;
  float* y2 = h;  // h free after scatter; reuse for GEMM2 output

  float* out_feats = (float*)d_out;
  float* out_read  = out_feats + NH;
  float* out_vf    = out_read + (size_t)GNUM * HDIM;
  float* z = out_feats;  // z lives in the feats output region during each layer

  dim3 blk(256);
  const int gridNH4 = (int)((NH / 4 + 255) / 256);

  k_init_vf<<<(GNUM * HDIM + 255) / 256, blk, 0, stream>>>(vn_emb, vf);

  for (int i = 0; i < L; ++i) {
    const float* fin = (i == 0) ? x : out_feats;
    k_h_init<<<gridNH4, blk, 0, stream>>>(fin, vf, batch, h, z, N, i > 0 ? 1 : 0);

    long long sc_total = (long long)E * 32;
    k_scatter<<<(int)((sc_total + 255) / 256), blk, 0, stream>>>(h, ei, z, E);

    // GEMM1: y1 = z @ W1[i] + b1[i]
    hipMemsetAsync(sum1, 0, (size_t)(H2DIM * 2) * sizeof(float), stream);
    k_gemm<<<dim3((N + 63) / 64, H2DIM / 64), blk, 0, stream>>>(
        z, conv_w1 + (size_t)i * HDIM * H2DIM, conv_b1 + (size_t)i * H2DIM,
        nullptr, nullptr, y1, N, HDIM, H2DIM);
    k_colstats<<<(N + 127) / 128, H2DIM, 0, stream>>>(y1, N, H2DIM, 128, sum1, ss1);
    k_bnfin<<<1, H2DIM, 0, stream>>>(sum1, ss1, conv_bng + (size_t)i * H2DIM,
                                     conv_bnb + (size_t)i * H2DIM,
                                     scale1, shift1, H2DIM, 1.0f / N);

    // GEMM2: y2 = relu(bn(y1)) @ W2[i] + b2[i]
    hipMemsetAsync(sum2, 0, (size_t)(HDIM * 2) * sizeof(float), stream);
    k_gemm<<<dim3((N + 63) / 64, HDIM / 64), blk, 0, stream>>>(
        y1, conv_w2 + (size_t)i * H2DIM * HDIM, conv_b2 + (size_t)i * HDIM,
        scale1, shift1, y2, N, H2DIM, HDIM);
    k_colstats<<<(N + 127) / 128, HDIM, 0, stream>>>(y2, N, HDIM, 128, sum2, ss2);
    k_bnfin<<<1, HDIM, 0, stream>>>(sum2, ss2, bn_g + (size_t)i * HDIM,
                                    bn_b + (size_t)i * HDIM,
                                    scale2, shift2, HDIM, 1.0f / N);
    // outer BN (+ReLU except last layer) -> feats
    k_bnapply<<<gridNH4, blk, 0, stream>>>(y2, scale2, shift2, out_feats,
                                           (long long)(NH / 4), HDIM / 4,
                                           (i < L - 1) ? 1 : 0);

    if (i == 1) {  // virtual-node MLP update
      hipMemsetAsync(pooled, 0, (size_t)GNUM * HDIM * sizeof(float), stream);
      k_pool<<<(int)((NH + 255) / 256), blk, 0, stream>>>(out_feats, batch, pooled, N);
      k_add<<<(GNUM * HDIM + 255) / 256, blk, 0, stream>>>(pooled, vf, vin, GNUM * HDIM);

      hipMemsetAsync(sum1, 0, (size_t)(H2DIM * 2) * sizeof(float), stream);
      k_gemm<<<dim3(GNUM / 64, H2DIM / 64), blk, 0, stream>>>(
          vin, vw1, vb1, nullptr, nullptr, v1, GNUM, HDIM, H2DIM);
      k_colstats<<<(GNUM + 127) / 128, H2DIM, 0, stream>>>(v1, GNUM, H2DIM, 128, sum1, ss1);
      k_bnfin<<<1, H2DIM, 0, stream>>>(sum1, ss1, vbn1g, vbn1b, scale1, shift1,
                                       H2DIM, 1.0f / GNUM);

      hipMemsetAsync(sum2, 0, (size_t)(HDIM * 2) * sizeof(float), stream);
      k_gemm<<<dim3(GNUM / 64, HDIM / 64), blk, 0, stream>>>(
          v1, vw2, vb2, scale1, shift1, vin /* v2 */, GNUM, H2DIM, HDIM);
      k_colstats<<<(GNUM + 127) / 128, HDIM, 0, stream>>>(vin, GNUM, HDIM, 128, sum2, ss2);
      k_bnfin<<<1, HDIM, 0, stream>>>(sum2, ss2, vbn2g, vbn2b, scale2, shift2,
                                      HDIM, 1.0f / GNUM);
      k_bnapply<<<(GNUM * HDIM / 4 + 255) / 256, blk, 0, stream>>>(
          vin, scale2, shift2, vf, (long long)(GNUM * HDIM / 4), HDIM / 4, 1);
    }
  }

  // readout: mean pool of final feats
  hipMemsetAsync(pooled, 0, (size_t)GNUM * HDIM * sizeof(float), stream);
  hipMemsetAsync(counts, 0, (size_t)GNUM * sizeof(float), stream);
  k_pool<<<(int)((NH + 255) / 256), blk, 0, stream>>>(out_feats, batch, pooled, N);
  k_counts<<<(N + 255) / 256, blk, 0, stream>>>(batch, counts, N);
  k_readout<<<(GNUM * HDIM + 255) / 256, blk, 0, stream>>>(pooled, counts, out_read,
                                                           GNUM * HDIM);
  hipMemcpyAsync(out_vf, vf, (size_t)GNUM * HDIM * sizeof(float),
                 hipMemcpyDeviceToDevice, stream);
}

// Round 2
// 2279.241 us; speedup vs baseline: 4.2535x; 4.2535x over previous
//
#include <hip/hip_runtime.h>

// GIN encoder w/ virtual node, 3 layers, H=128. Full f32 implementation.
// Round 2: CSR gather-sum aggregation replaces atomic scatter (was 83% of time).

#define HDIM 128
#define H2DIM 256
#define GNUM 512
#define BN_EPS 1e-5f

// ---------------- elementwise / init ----------------

__global__ __launch_bounds__(256) void k_init_vf(const float* __restrict__ emb,
                                                 float* __restrict__ vf) {
  int idx = blockIdx.x * 256 + threadIdx.x;
  if (idx < GNUM * HDIM) vf[idx] = emb[idx & (HDIM - 1)];
}

// h = feats (+ vf[batch])
__global__ __launch_bounds__(256) void k_h_init(const float* __restrict__ feats,
                                                const float* __restrict__ vf,
                                                const int* __restrict__ batch,
                                                float* __restrict__ h,
                                                int N, int useVf) {
  int idx = blockIdx.x * 256 + threadIdx.x;
  int total = N * (HDIM / 4);
  if (idx >= total) return;
  int n = idx >> 5;          // HDIM/4 == 32
  int c4 = idx & 31;
  float4 v = ((const float4*)feats)[idx];
  if (useVf) {
    int g = batch[n];
    float4 w = ((const float4*)(vf + (size_t)g * HDIM))[c4];
    v.x += w.x; v.y += w.y; v.z += w.z; v.w += w.w;
  }
  ((float4*)h)[idx] = v;
}

// ---------------- CSR build (once per call, reused by all layers) ----------------

__global__ __launch_bounds__(256) void k_hist(const int* __restrict__ ei,
                                              int* __restrict__ deg, int E) {
  int e = blockIdx.x * 256 + threadIdx.x;
  if (e < E) atomicAdd(&deg[ei[E + e]], 1);
}

// single-block exclusive scan over deg[0..N) -> row_ptr[0..N]
__global__ __launch_bounds__(1024) void k_scan(const int* __restrict__ deg,
                                               int* __restrict__ row_ptr, int N) {
  __shared__ int psum[1024];
  int tid = threadIdx.x;
  int chunk = (N + 1023) / 1024;
  int start = tid * chunk;
  int end = min(start + chunk, N);
  int s = 0;
  for (int i = start; i < end; ++i) s += deg[i];
  psum[tid] = s;
  __syncthreads();
  for (int off = 1; off < 1024; off <<= 1) {
    int v = (tid >= off) ? psum[tid - off] : 0;
    __syncthreads();
    psum[tid] += v;
    __syncthreads();
  }
  int base = (tid == 0) ? 0 : psum[tid - 1];
  for (int i = start; i < end; ++i) {
    row_ptr[i] = base;
    base += deg[i];
  }
  if (tid == 1023) row_ptr[N] = psum[1023];
}

__global__ __launch_bounds__(256) void k_fill(const int* __restrict__ ei,
                                              int* __restrict__ cursor,
                                              int* __restrict__ csr, int E) {
  int e = blockIdx.x * 256 + threadIdx.x;
  if (e >= E) return;
  int d = ei[E + e];
  int pos = atomicAdd(&cursor[d], 1);
  csr[pos] = ei[e];
}

// ---------------- aggregation: z[n] = h[n] + sum_{s in N(n)} h[s] ----------------
// one 64-lane wave per node; lane owns a float2 column (128 floats = 64 x float2)
__global__ __launch_bounds__(256) void k_aggregate(const float* __restrict__ h,
                                                   const int* __restrict__ row_ptr,
                                                   const int* __restrict__ csr,
                                                   float* __restrict__ z, int N) {
  int n = blockIdx.x * 4 + (threadIdx.x >> 6);
  if (n >= N) return;
  int lane = threadIdx.x & 63;
  const float2* __restrict__ h2 = (const float2*)h;
  float2 acc = h2[(size_t)n * 64 + lane];
  int beg = row_ptr[n], end = row_ptr[n + 1];
  int j = beg;
  for (; j + 4 <= end; j += 4) {
    int s0 = csr[j + 0], s1 = csr[j + 1], s2 = csr[j + 2], s3 = csr[j + 3];
    float2 v0 = h2[(size_t)s0 * 64 + lane];
    float2 v1 = h2[(size_t)s1 * 64 + lane];
    float2 v2 = h2[(size_t)s2 * 64 + lane];
    float2 v3 = h2[(size_t)s3 * 64 + lane];
    acc.x += v0.x + v1.x + v2.x + v3.x;
    acc.y += v0.y + v1.y + v2.y + v3.y;
  }
  for (; j < end; ++j) {
    int s = csr[j];
    float2 v = h2[(size_t)s * 64 + lane];
    acc.x += v.x; acc.y += v.y;
  }
  ((float2*)z)[(size_t)n * 64 + lane] = acc;
}

// ---------------- GEMM: C = act(A) @ B + bias ----------------
__global__ __launch_bounds__(256) void k_gemm(const float* __restrict__ A,
                                              const float* __restrict__ B,
                                              const float* __restrict__ bias,
                                              const float* __restrict__ kscale,
                                              const float* __restrict__ kshift,
                                              float* __restrict__ C,
                                              int M, int K, int Nc) {
  __shared__ float As[16][65];
  __shared__ float Bs[16][65];
  int tid = threadIdx.x;
  int bm = blockIdx.x * 64;
  int bn = blockIdx.y * 64;
  int trow = (tid >> 4) << 2;
  int tcol = (tid & 15) << 2;
  float acc[4][4];
#pragma unroll
  for (int r = 0; r < 4; ++r)
#pragma unroll
    for (int c = 0; c < 4; ++c) acc[r][c] = 0.f;

  int arow = tid >> 2;
  int ak = (tid & 3) << 2;
  int bt4 = tid << 2;
  int bk = bt4 >> 6;
  int bcol = bt4 & 63;

  for (int kt = 0; kt < K; kt += 16) {
    float4 av = make_float4(0.f, 0.f, 0.f, 0.f);
    int grow = bm + arow;
    if (grow < M) av = *(const float4*)(A + (size_t)grow * K + kt + ak);
    if (kscale) {
      int k0 = kt + ak;
      av.x = fmaxf(fmaf(av.x, kscale[k0 + 0], kshift[k0 + 0]), 0.f);
      av.y = fmaxf(fmaf(av.y, kscale[k0 + 1], kshift[k0 + 1]), 0.f);
      av.z = fmaxf(fmaf(av.z, kscale[k0 + 2], kshift[k0 + 2]), 0.f);
      av.w = fmaxf(fmaf(av.w, kscale[k0 + 3], kshift[k0 + 3]), 0.f);
    }
    float4 bv = *(const float4*)(B + (size_t)(kt + bk) * Nc + bn + bcol);
    __syncthreads();
    As[ak + 0][arow] = av.x;
    As[ak + 1][arow] = av.y;
    As[ak + 2][arow] = av.z;
    As[ak + 3][arow] = av.w;
    Bs[bk][bcol + 0] = bv.x;
    Bs[bk][bcol + 1] = bv.y;
    Bs[bk][bcol + 2] = bv.z;
    Bs[bk][bcol + 3] = bv.w;
    __syncthreads();
#pragma unroll
    for (int k = 0; k < 16; ++k) {
      float a0 = As[k][trow + 0], a1 = As[k][trow + 1];
      float a2 = As[k][trow + 2], a3 = As[k][trow + 3];
      float b0 = Bs[k][tcol + 0], b1 = Bs[k][tcol + 1];
      float b2 = Bs[k][tcol + 2], b3 = Bs[k][tcol + 3];
      acc[0][0] = fmaf(a0, b0, acc[0][0]); acc[0][1] = fmaf(a0, b1, acc[0][1]);
      acc[0][2] = fmaf(a0, b2, acc[0][2]); acc[0][3] = fmaf(a0, b3, acc[0][3]);
      acc[1][0] = fmaf(a1, b0, acc[1][0]); acc[1][1] = fmaf(a1, b1, acc[1][1]);
      acc[1][2] = fmaf(a1, b2, acc[1][2]); acc[1][3] = fmaf(a1, b3, acc[1][3]);
      acc[2][0] = fmaf(a2, b0, acc[2][0]); acc[2][1] = fmaf(a2, b1, acc[2][1]);
      acc[2][2] = fmaf(a2, b2, acc[2][2]); acc[2][3] = fmaf(a2, b3, acc[2][3]);
      acc[3][0] = fmaf(a3, b0, acc[3][0]); acc[3][1] = fmaf(a3, b1, acc[3][1]);
      acc[3][2] = fmaf(a3, b2, acc[3][2]); acc[3][3] = fmaf(a3, b3, acc[3][3]);
    }
  }
#pragma unroll
  for (int r = 0; r < 4; ++r) {
    int grow = bm + trow + r;
    if (grow < M) {
      float4 o;
      o.x = acc[r][0] + bias[bn + tcol + 0];
      o.y = acc[r][1] + bias[bn + tcol + 1];
      o.z = acc[r][2] + bias[bn + tcol + 2];
      o.w = acc[r][3] + bias[bn + tcol + 3];
      *(float4*)(C + (size_t)grow * Nc + bn + tcol) = o;
    }
  }
}

// ---------------- BN stats / finalize / apply ----------------

__global__ void k_colstats(const float* __restrict__ Y, int M, int C, int stripe,
                           float* __restrict__ sum, float* __restrict__ sumsq) {
  int c = threadIdx.x;
  int r0 = blockIdx.x * stripe;
  int r1 = min(r0 + stripe, M);
  float s = 0.f, ss = 0.f;
  for (int r = r0; r < r1; ++r) {
    float v = Y[(size_t)r * C + c];
    s += v; ss += v * v;
  }
  atomicAdd(&sum[c], s);
  atomicAdd(&sumsq[c], ss);
}

__global__ void k_bnfin(const float* __restrict__ sum, const float* __restrict__ sumsq,
                        const float* __restrict__ g, const float* __restrict__ b,
                        float* __restrict__ scale, float* __restrict__ shift,
                        int C, float invM) {
  int c = threadIdx.x;
  if (c >= C) return;
  float mean = sum[c] * invM;
  float var = sumsq[c] * invM - mean * mean;
  float inv = rsqrtf(var + BN_EPS);
  float sc = g[c] * inv;
  scale[c] = sc;
  shift[c] = fmaf(-mean, sc, b[c]);
}

__global__ __launch_bounds__(256) void k_bnapply(const float* __restrict__ Y,
                                                 const float* __restrict__ scale,
                                                 const float* __restrict__ shift,
                                                 float* __restrict__ out,
                                                 long long total4, int Cq, int relu) {
  long long idx = (long long)blockIdx.x * 256 + threadIdx.x;
  if (idx >= total4) return;
  int c = (int)(idx % Cq) * 4;
  float4 v = ((const float4*)Y)[idx];
  v.x = fmaf(v.x, scale[c + 0], shift[c + 0]);
  v.y = fmaf(v.y, scale[c + 1], shift[c + 1]);
  v.z = fmaf(v.z, scale[c + 2], shift[c + 2]);
  v.w = fmaf(v.w, scale[c + 3], shift[c + 3]);
  if (relu) {
    v.x = fmaxf(v.x, 0.f); v.y = fmaxf(v.y, 0.f);
    v.z = fmaxf(v.z, 0.f); v.w = fmaxf(v.w, 0.f);
  }
  ((float4*)out)[idx] = v;
}

// ---------------- pooling / readout / small ops ----------------

__global__ __launch_bounds__(256) void k_pool(const float* __restrict__ X,
                                              const int* __restrict__ batch,
                                              float* __restrict__ pooled, int N) {
  int idx = blockIdx.x * 256 + threadIdx.x;
  if (idx >= N * HDIM) return;
  int n = idx >> 7;
  int c = idx & 127;
  atomicAdd(&pooled[(size_t)batch[n] * HDIM + c], X[idx]);
}

__global__ __launch_bounds__(256) void k_counts(const int* __restrict__ batch,
                                                float* __restrict__ counts, int N) {
  int n = blockIdx.x * 256 + threadIdx.x;
  if (n < N) atomicAdd(&counts[batch[n]], 1.0f);
}

__global__ __launch_bounds__(256) void k_add(const float* __restrict__ a,
                                             const float* __restrict__ b,
                                             float* __restrict__ o, int n) {
  int idx = blockIdx.x * 256 + threadIdx.x;
  if (idx < n) o[idx] = a[idx] + b[idx];
}

__global__ __launch_bounds__(256) void k_readout(const float* __restrict__ pooled,
                                                 const float* __restrict__ counts,
                                                 float* __restrict__ out, int n) {
  int idx = blockIdx.x * 256 + threadIdx.x;
  if (idx >= n) return;
  int g = idx >> 7;
  out[idx] = pooled[idx] / fmaxf(counts[g], 1.0f);
}

// ---------------- launch ----------------

extern "C" void kernel_launch(void* const* d_in, const int* in_sizes, int n_in,
                              void* d_out, int out_size, void* d_ws, size_t ws_size,
                              hipStream_t stream) {
  const float* x       = (const float*)d_in[0];
  const int*   ei      = (const int*)d_in[1];
  const int*   batch   = (const int*)d_in[2];
  const float* conv_w1 = (const float*)d_in[4];
  const float* conv_b1 = (const float*)d_in[5];
  const float* conv_bng = (const float*)d_in[6];
  const float* conv_bnb = (const float*)d_in[7];
  const float* conv_w2 = (const float*)d_in[8];
  const float* conv_b2 = (const float*)d_in[9];
  const float* bn_g    = (const float*)d_in[10];
  const float* bn_b    = (const float*)d_in[11];
  const float* vn_emb  = (const float*)d_in[12];
  const float* vw1     = (const float*)d_in[13];
  const float* vb1     = (const float*)d_in[14];
  const float* vbn1g   = (const float*)d_in[15];
  const float* vbn1b   = (const float*)d_in[16];
  const float* vw2     = (const float*)d_in[17];
  const float* vb2     = (const float*)d_in[18];
  const float* vbn2g   = (const float*)d_in[19];
  const float* vbn2b   = (const float*)d_in[20];

  const int N = in_sizes[2];
  const int E = in_sizes[1] / 2;
  const int L = 3;

  const size_t NH  = (size_t)N * HDIM;
  const size_t NH2 = (size_t)N * H2DIM;

  // workspace layout (~162 MB): h | y1 | stats | vf | pooled | vin | v1 | counts | CSR
  float* h      = (float*)d_ws;
  float* y1     = h + NH;
  float* sum1   = y1 + NH2;
  float* ss1    = sum1 + H2DIM;
  float* sum2   = ss1 + H2DIM;
  float* ss2    = sum2 + HDIM;
  float* scale1 = ss2 + HDIM;
  float* shift1 = scale1 + H2DIM;
  float* scale2 = shift1 + H2DIM;
  float* shift2 = scale2 + HDIM;
  float* vf     = shift2 + HDIM;
  float* pooled = vf + (size_t)GNUM * HDIM;
  float* vin    = pooled + (size_t)GNUM * HDIM;
  float* v1     = vin + (size_t)GNUM * HDIM;
  float* counts = v1 + (size_t)GNUM * H2DIM;
  int*   cursor = (int*)(counts + GNUM);   // doubles as deg during build
  int*   row_ptr = cursor + N;
  int*   csr    = row_ptr + N + 1;
  float* y2 = h;  // h free after aggregate+GEMM1; reuse for GEMM2 output

  float* out_feats = (float*)d_out;
  float* out_read  = out_feats + NH;
  float* out_vf    = out_read + (size_t)GNUM * HDIM;
  float* z = out_feats;  // aggregation output lives in the feats output region

  dim3 blk(256);
  const int gridNH4 = (int)((NH / 4 + 255) / 256);
  const int gridE = (E + 255) / 256;

  // ---- CSR build (once; edge_index constant within a call) ----
  hipMemsetAsync(cursor, 0, (size_t)N * sizeof(int), stream);
  k_hist<<<gridE, blk, 0, stream>>>(ei, cursor, E);
  k_scan<<<1, 1024, 0, stream>>>(cursor, row_ptr, N);
  hipMemcpyAsync(cursor, row_ptr, (size_t)N * sizeof(int),
                 hipMemcpyDeviceToDevice, stream);
  k_fill<<<gridE, blk, 0, stream>>>(ei, cursor, csr, E);

  k_init_vf<<<(GNUM * HDIM + 255) / 256, blk, 0, stream>>>(vn_emb, vf);

  for (int i = 0; i < L; ++i) {
    const float* fin = (i == 0) ? x : out_feats;
    k_h_init<<<gridNH4, blk, 0, stream>>>(fin, vf, batch, h, N, i > 0 ? 1 : 0);

    // z = h + gather-sum of neighbors
    k_aggregate<<<(N + 3) / 4, blk, 0, stream>>>(h, row_ptr, csr, z, N);

    // GEMM1: y1 = z @ W1[i] + b1[i]
    hipMemsetAsync(sum1, 0, (size_t)(H2DIM * 2) * sizeof(float), stream);
    k_gemm<<<dim3((N + 63) / 64, H2DIM / 64), blk, 0, stream>>>(
        z, conv_w1 + (size_t)i * HDIM * H2DIM, conv_b1 + (size_t)i * H2DIM,
        nullptr, nullptr, y1, N, HDIM, H2DIM);
    k_colstats<<<(N + 127) / 128, H2DIM, 0, stream>>>(y1, N, H2DIM, 128, sum1, ss1);
    k_bnfin<<<1, H2DIM, 0, stream>>>(sum1, ss1, conv_bng + (size_t)i * H2DIM,
                                     conv_bnb + (size_t)i * H2DIM,
                                     scale1, shift1, H2DIM, 1.0f / N);

    // GEMM2: y2 = relu(bn(y1)) @ W2[i] + b2[i]
    hipMemsetAsync(sum2, 0, (size_t)(HDIM * 2) * sizeof(float), stream);
    k_gemm<<<dim3((N + 63) / 64, HDIM / 64), blk, 0, stream>>>(
        y1, conv_w2 + (size_t)i * H2DIM * HDIM, conv_b2 + (size_t)i * HDIM,
        scale1, shift1, y2, N, H2DIM, HDIM);
    k_colstats<<<(N + 127) / 128, HDIM, 0, stream>>>(y2, N, HDIM, 128, sum2, ss2);
    k_bnfin<<<1, HDIM, 0, stream>>>(sum2, ss2, bn_g + (size_t)i * HDIM,
                                    bn_b + (size_t)i * HDIM,
                                    scale2, shift2, HDIM, 1.0f / N);
    k_bnapply<<<gridNH4, blk, 0, stream>>>(y2, scale2, shift2, out_feats,
                                           (long long)(NH / 4), HDIM / 4,
                                           (i < L - 1) ? 1 : 0);

    if (i == 1) {  // virtual-node MLP update
      hipMemsetAsync(pooled, 0, (size_t)GNUM * HDIM * sizeof(float), stream);
      k_pool<<<(int)((NH + 255) / 256), blk, 0, stream>>>(out_feats, batch, pooled, N);
      k_add<<<(GNUM * HDIM + 255) / 256, blk, 0, stream>>>(pooled, vf, vin, GNUM * HDIM);

      hipMemsetAsync(sum1, 0, (size_t)(H2DIM * 2) * sizeof(float), stream);
      k_gemm<<<dim3(GNUM / 64, H2DIM / 64), blk, 0, stream>>>(
          vin, vw1, vb1, nullptr, nullptr, v1, GNUM, HDIM, H2DIM);
      k_colstats<<<(GNUM + 127) / 128, H2DIM, 0, stream>>>(v1, GNUM, H2DIM, 128, sum1, ss1);
      k_bnfin<<<1, H2DIM, 0, stream>>>(sum1, ss1, vbn1g, vbn1b, scale1, shift1,
                                       H2DIM, 1.0f / GNUM);

      hipMemsetAsync(sum2, 0, (size_t)(HDIM * 2) * sizeof(float), stream);
      k_gemm<<<dim3(GNUM / 64, HDIM / 64), blk, 0, stream>>>(
          v1, vw2, vb2, scale1, shift1, vin /* v2 */, GNUM, H2DIM, HDIM);
      k_colstats<<<(GNUM + 127) / 128, HDIM, 0, stream>>>(vin, GNUM, HDIM, 128, sum2, ss2);
      k_bnfin<<<1, HDIM, 0, stream>>>(sum2, ss2, vbn2g, vbn2b, scale2, shift2,
                                      HDIM, 1.0f / GNUM);
      k_bnapply<<<(GNUM * HDIM / 4 + 255) / 256, blk, 0, stream>>>(
          vin, scale2, shift2, vf, (long long)(GNUM * HDIM / 4), HDIM / 4, 1);
    }
  }

  // readout: mean pool of final feats
  hipMemsetAsync(pooled, 0, (size_t)GNUM * HDIM * sizeof(float), stream);
  hipMemsetAsync(counts, 0, (size_t)GNUM * sizeof(float), stream);
  k_pool<<<(int)((NH + 255) / 256), blk, 0, stream>>>(out_feats, batch, pooled, N);
  k_counts<<<(N + 255) / 256, blk, 0, stream>>>(batch, counts, N);
  k_readout<<<(GNUM * HDIM + 255) / 256, blk, 0, stream>>>(pooled, counts, out_read,
                                                           GNUM * HDIM);
  hipMemcpyAsync(out_vf, vf, (size_t)GNUM * HDIM * sizeof(float),
                 hipMemcpyDeviceToDevice, stream);
}

// Round 3
// 1866.483 us; speedup vs baseline: 5.1941x; 1.2211x over previous
//
#include <hip/hip_runtime.h>

// GIN encoder w/ virtual node, 3 layers, H=128. Full f32 implementation.
// Round 3: fast decoupled scan (was 163us single-block) + 128x128/8x8 GEMM tile.

#define HDIM 128
#define H2DIM 256
#define GNUM 512
#define BN_EPS 1e-5f

// ---------------- elementwise / init ----------------

__global__ __launch_bounds__(256) void k_init_vf(const float* __restrict__ emb,
                                                 float* __restrict__ vf) {
  int idx = blockIdx.x * 256 + threadIdx.x;
  if (idx < GNUM * HDIM) vf[idx] = emb[idx & (HDIM - 1)];
}

// h = feats (+ vf[batch])
__global__ __launch_bounds__(256) void k_h_init(const float* __restrict__ feats,
                                                const float* __restrict__ vf,
                                                const int* __restrict__ batch,
                                                float* __restrict__ h,
                                                int N, int useVf) {
  int idx = blockIdx.x * 256 + threadIdx.x;
  int total = N * (HDIM / 4);
  if (idx >= total) return;
  int n = idx >> 5;
  int c4 = idx & 31;
  float4 v = ((const float4*)feats)[idx];
  if (useVf) {
    int g = batch[n];
    float4 w = ((const float4*)(vf + (size_t)g * HDIM))[c4];
    v.x += w.x; v.y += w.y; v.z += w.z; v.w += w.w;
  }
  ((float4*)h)[idx] = v;
}

// ---------------- CSR build (once per call, reused by all layers) ----------------

__global__ __launch_bounds__(256) void k_hist(const int* __restrict__ ei,
                                              int* __restrict__ deg, int E) {
  int e = blockIdx.x * 256 + threadIdx.x;
  if (e < E) atomicAdd(&deg[ei[E + e]], 1);
}

// phase 1: per-block sums over 2048-element chunks
__global__ __launch_bounds__(256) void k_scan1(const int* __restrict__ deg,
                                               int* __restrict__ bsum, int N) {
  __shared__ int sh[256];
  int t = threadIdx.x;
  int base = blockIdx.x * 2048 + t * 8;
  int s = 0;
#pragma unroll
  for (int j = 0; j < 8; ++j) {
    int i = base + j;
    if (i < N) s += deg[i];
  }
  sh[t] = s;
  __syncthreads();
  for (int off = 128; off > 0; off >>= 1) {
    if (t < off) sh[t] += sh[t + off];
    __syncthreads();
  }
  if (t == 0) bsum[blockIdx.x] = sh[0];
}

// phase 2: exclusive scan of block sums (nb <= 256); writes row_ptr[N]=total
__global__ __launch_bounds__(256) void k_scan2(int* __restrict__ bsum, int nb,
                                               int* __restrict__ row_ptr, int N) {
  __shared__ int sh[256];
  int t = threadIdx.x;
  int v = (t < nb) ? bsum[t] : 0;
  sh[t] = v;
  __syncthreads();
  for (int off = 1; off < 256; off <<= 1) {
    int add = (t >= off) ? sh[t - off] : 0;
    __syncthreads();
    sh[t] += add;
    __syncthreads();
  }
  if (t < nb) bsum[t] = sh[t] - v;  // exclusive block offset
  if (t == 255) row_ptr[N] = sh[255];
}

// phase 3: per-block exclusive scan + offset; writes row_ptr and cursor (in-place over deg)
__global__ __launch_bounds__(256) void k_scan3(const int* __restrict__ deg,
                                               const int* __restrict__ boff,
                                               int* __restrict__ row_ptr,
                                               int* __restrict__ cursor, int N) {
  __shared__ int sh[256];
  int t = threadIdx.x;
  int base = blockIdx.x * 2048 + t * 8;
  int d[8];
  int s = 0;
#pragma unroll
  for (int j = 0; j < 8; ++j) {
    int i = base + j;
    d[j] = (i < N) ? deg[i] : 0;
    s += d[j];
  }
  sh[t] = s;
  __syncthreads();
  for (int off = 1; off < 256; off <<= 1) {
    int add = (t >= off) ? sh[t - off] : 0;
    __syncthreads();
    sh[t] += add;
    __syncthreads();
  }
  int run = boff[blockIdx.x] + sh[t] - s;
#pragma unroll
  for (int j = 0; j < 8; ++j) {
    int i = base + j;
    if (i < N) {
      row_ptr[i] = run;
      cursor[i] = run;
      run += d[j];
    }
  }
}

__global__ __launch_bounds__(256) void k_fill(const int* __restrict__ ei,
                                              int* __restrict__ cursor,
                                              int* __restrict__ csr, int E) {
  int e = blockIdx.x * 256 + threadIdx.x;
  if (e >= E) return;
  int d = ei[E + e];
  int pos = atomicAdd(&cursor[d], 1);
  csr[pos] = ei[e];
}

// ---------------- aggregation: z[n] = h[n] + sum_{s in N(n)} h[s] ----------------
__global__ __launch_bounds__(256) void k_aggregate(const float* __restrict__ h,
                                                   const int* __restrict__ row_ptr,
                                                   const int* __restrict__ csr,
                                                   float* __restrict__ z, int N) {
  int n = blockIdx.x * 4 + (threadIdx.x >> 6);
  if (n >= N) return;
  int lane = threadIdx.x & 63;
  const float2* __restrict__ h2 = (const float2*)h;
  float2 acc = h2[(size_t)n * 64 + lane];
  int beg = row_ptr[n], end = row_ptr[n + 1];
  int j = beg;
  for (; j + 4 <= end; j += 4) {
    int s0 = csr[j + 0], s1 = csr[j + 1], s2 = csr[j + 2], s3 = csr[j + 3];
    float2 v0 = h2[(size_t)s0 * 64 + lane];
    float2 v1 = h2[(size_t)s1 * 64 + lane];
    float2 v2 = h2[(size_t)s2 * 64 + lane];
    float2 v3 = h2[(size_t)s3 * 64 + lane];
    acc.x += v0.x + v1.x + v2.x + v3.x;
    acc.y += v0.y + v1.y + v2.y + v3.y;
  }
  for (; j < end; ++j) {
    int s = csr[j];
    float2 v = h2[(size_t)s * 64 + lane];
    acc.x += v.x; acc.y += v.y;
  }
  ((float2*)z)[(size_t)n * 64 + lane] = acc;
}

// ---------------- GEMM 128x128 tile, 8x8 microtile: C = act(A) @ B + bias ----------
__global__ __launch_bounds__(256) void k_gemm128(const float* __restrict__ A,
                                                 const float* __restrict__ B,
                                                 const float* __restrict__ bias,
                                                 const float* __restrict__ kscale,
                                                 const float* __restrict__ kshift,
                                                 float* __restrict__ C,
                                                 int M, int K, int Nc) {
  __shared__ __align__(16) float As[16][132];  // As[k][row], row-padded to 132
  __shared__ __align__(16) float Bs[16][132];  // Bs[k][col]
  int tid = threadIdx.x;
  int bm = blockIdx.x * 128;
  int bn = blockIdx.y * 128;
  int tr = (tid >> 4) * 8;   // 0..120
  int tc = (tid & 15) * 8;   // 0..120
  float acc[8][8] = {};

  int arow = tid >> 1;          // 0..127
  int ak = (tid & 1) * 8;       // 0 or 8
  int brow = tid >> 4;          // 0..15
  int bcol = (tid & 15) * 8;    // 0..120

  for (int kt = 0; kt < K; kt += 16) {
    float4 a0 = make_float4(0.f, 0.f, 0.f, 0.f);
    float4 a1 = make_float4(0.f, 0.f, 0.f, 0.f);
    int grow = bm + arow;
    if (grow < M) {
      const float* ap = A + (size_t)grow * K + kt + ak;
      a0 = *(const float4*)ap;
      a1 = *(const float4*)(ap + 4);
    }
    if (kscale) {
      int k0 = kt + ak;
      a0.x = fmaxf(fmaf(a0.x, kscale[k0 + 0], kshift[k0 + 0]), 0.f);
      a0.y = fmaxf(fmaf(a0.y, kscale[k0 + 1], kshift[k0 + 1]), 0.f);
      a0.z = fmaxf(fmaf(a0.z, kscale[k0 + 2], kshift[k0 + 2]), 0.f);
      a0.w = fmaxf(fmaf(a0.w, kscale[k0 + 3], kshift[k0 + 3]), 0.f);
      a1.x = fmaxf(fmaf(a1.x, kscale[k0 + 4], kshift[k0 + 4]), 0.f);
      a1.y = fmaxf(fmaf(a1.y, kscale[k0 + 5], kshift[k0 + 5]), 0.f);
      a1.z = fmaxf(fmaf(a1.z, kscale[k0 + 6], kshift[k0 + 6]), 0.f);
      a1.w = fmaxf(fmaf(a1.w, kscale[k0 + 7], kshift[k0 + 7]), 0.f);
    }
    const float* bp = B + (size_t)(kt + brow) * Nc + bn + bcol;
    float4 b0 = *(const float4*)bp;
    float4 b1 = *(const float4*)(bp + 4);
    __syncthreads();
    As[ak + 0][arow] = a0.x;
    As[ak + 1][arow] = a0.y;
    As[ak + 2][arow] = a0.z;
    As[ak + 3][arow] = a0.w;
    As[ak + 4][arow] = a1.x;
    As[ak + 5][arow] = a1.y;
    As[ak + 6][arow] = a1.z;
    As[ak + 7][arow] = a1.w;
    *(float4*)&Bs[brow][bcol] = b0;
    *(float4*)&Bs[brow][bcol + 4] = b1;
    __syncthreads();
#pragma unroll
    for (int k = 0; k < 16; ++k) {
      float4 x0 = *(const float4*)&As[k][tr];
      float4 x1 = *(const float4*)&As[k][tr + 4];
      float4 y0 = *(const float4*)&Bs[k][tc];
      float4 y1 = *(const float4*)&Bs[k][tc + 4];
      float av[8] = {x0.x, x0.y, x0.z, x0.w, x1.x, x1.y, x1.z, x1.w};
      float bv[8] = {y0.x, y0.y, y0.z, y0.w, y1.x, y1.y, y1.z, y1.w};
#pragma unroll
      for (int r = 0; r < 8; ++r)
#pragma unroll
        for (int c = 0; c < 8; ++c)
          acc[r][c] = fmaf(av[r], bv[c], acc[r][c]);
    }
  }
  float bb[8];
#pragma unroll
  for (int c = 0; c < 8; ++c) bb[c] = bias[bn + tc + c];
#pragma unroll
  for (int r = 0; r < 8; ++r) {
    int grow = bm + tr + r;
    if (grow < M) {
      float* cp = C + (size_t)grow * Nc + bn + tc;
      float4 o0, o1;
      o0.x = acc[r][0] + bb[0]; o0.y = acc[r][1] + bb[1];
      o0.z = acc[r][2] + bb[2]; o0.w = acc[r][3] + bb[3];
      o1.x = acc[r][4] + bb[4]; o1.y = acc[r][5] + bb[5];
      o1.z = acc[r][6] + bb[6]; o1.w = acc[r][7] + bb[7];
      *(float4*)cp = o0;
      *(float4*)(cp + 4) = o1;
    }
  }
}

// ---------------- GEMM 64x64 (kept for tiny vn-MLP matrices) ----------------
__global__ __launch_bounds__(256) void k_gemm(const float* __restrict__ A,
                                              const float* __restrict__ B,
                                              const float* __restrict__ bias,
                                              const float* __restrict__ kscale,
                                              const float* __restrict__ kshift,
                                              float* __restrict__ C,
                                              int M, int K, int Nc) {
  __shared__ float As[16][65];
  __shared__ float Bs[16][65];
  int tid = threadIdx.x;
  int bm = blockIdx.x * 64;
  int bn = blockIdx.y * 64;
  int trow = (tid >> 4) << 2;
  int tcol = (tid & 15) << 2;
  float acc[4][4] = {};

  int arow = tid >> 2;
  int ak = (tid & 3) << 2;
  int bt4 = tid << 2;
  int bk = bt4 >> 6;
  int bcol = bt4 & 63;

  for (int kt = 0; kt < K; kt += 16) {
    float4 av = make_float4(0.f, 0.f, 0.f, 0.f);
    int grow = bm + arow;
    if (grow < M) av = *(const float4*)(A + (size_t)grow * K + kt + ak);
    if (kscale) {
      int k0 = kt + ak;
      av.x = fmaxf(fmaf(av.x, kscale[k0 + 0], kshift[k0 + 0]), 0.f);
      av.y = fmaxf(fmaf(av.y, kscale[k0 + 1], kshift[k0 + 1]), 0.f);
      av.z = fmaxf(fmaf(av.z, kscale[k0 + 2], kshift[k0 + 2]), 0.f);
      av.w = fmaxf(fmaf(av.w, kscale[k0 + 3], kshift[k0 + 3]), 0.f);
    }
    float4 bv = *(const float4*)(B + (size_t)(kt + bk) * Nc + bn + bcol);
    __syncthreads();
    As[ak + 0][arow] = av.x;
    As[ak + 1][arow] = av.y;
    As[ak + 2][arow] = av.z;
    As[ak + 3][arow] = av.w;
    Bs[bk][bcol + 0] = bv.x;
    Bs[bk][bcol + 1] = bv.y;
    Bs[bk][bcol + 2] = bv.z;
    Bs[bk][bcol + 3] = bv.w;
    __syncthreads();
#pragma unroll
    for (int k = 0; k < 16; ++k) {
      float a0 = As[k][trow + 0], a1 = As[k][trow + 1];
      float a2 = As[k][trow + 2], a3 = As[k][trow + 3];
      float b0 = Bs[k][tcol + 0], b1 = Bs[k][tcol + 1];
      float b2 = Bs[k][tcol + 2], b3 = Bs[k][tcol + 3];
      acc[0][0] = fmaf(a0, b0, acc[0][0]); acc[0][1] = fmaf(a0, b1, acc[0][1]);
      acc[0][2] = fmaf(a0, b2, acc[0][2]); acc[0][3] = fmaf(a0, b3, acc[0][3]);
      acc[1][0] = fmaf(a1, b0, acc[1][0]); acc[1][1] = fmaf(a1, b1, acc[1][1]);
      acc[1][2] = fmaf(a1, b2, acc[1][2]); acc[1][3] = fmaf(a1, b3, acc[1][3]);
      acc[2][0] = fmaf(a2, b0, acc[2][0]); acc[2][1] = fmaf(a2, b1, acc[2][1]);
      acc[2][2] = fmaf(a2, b2, acc[2][2]); acc[2][3] = fmaf(a2, b3, acc[2][3]);
      acc[3][0] = fmaf(a3, b0, acc[3][0]); acc[3][1] = fmaf(a3, b1, acc[3][1]);
      acc[3][2] = fmaf(a3, b2, acc[3][2]); acc[3][3] = fmaf(a3, b3, acc[3][3]);
    }
  }
#pragma unroll
  for (int r = 0; r < 4; ++r) {
    int grow = bm + trow + r;
    if (grow < M) {
      float4 o;
      o.x = acc[r][0] + bias[bn + tcol + 0];
      o.y = acc[r][1] + bias[bn + tcol + 1];
      o.z = acc[r][2] + bias[bn + tcol + 2];
      o.w = acc[r][3] + bias[bn + tcol + 3];
      *(float4*)(C + (size_t)grow * Nc + bn + tcol) = o;
    }
  }
}

// ---------------- BN stats / finalize / apply ----------------

__global__ void k_colstats(const float* __restrict__ Y, int M, int C, int stripe,
                           float* __restrict__ sum, float* __restrict__ sumsq) {
  int c = threadIdx.x;
  int r0 = blockIdx.x * stripe;
  int r1 = min(r0 + stripe, M);
  float s = 0.f, ss = 0.f;
  for (int r = r0; r < r1; ++r) {
    float v = Y[(size_t)r * C + c];
    s += v; ss += v * v;
  }
  atomicAdd(&sum[c], s);
  atomicAdd(&sumsq[c], ss);
}

__global__ void k_bnfin(const float* __restrict__ sum, const float* __restrict__ sumsq,
                        const float* __restrict__ g, const float* __restrict__ b,
                        float* __restrict__ scale, float* __restrict__ shift,
                        int C, float invM) {
  int c = threadIdx.x;
  if (c >= C) return;
  float mean = sum[c] * invM;
  float var = sumsq[c] * invM - mean * mean;
  float inv = rsqrtf(var + BN_EPS);
  float sc = g[c] * inv;
  scale[c] = sc;
  shift[c] = fmaf(-mean, sc, b[c]);
}

__global__ __launch_bounds__(256) void k_bnapply(const float* __restrict__ Y,
                                                 const float* __restrict__ scale,
                                                 const float* __restrict__ shift,
                                                 float* __restrict__ out,
                                                 long long total4, int Cq, int relu) {
  long long idx = (long long)blockIdx.x * 256 + threadIdx.x;
  if (idx >= total4) return;
  int c = (int)(idx % Cq) * 4;
  float4 v = ((const float4*)Y)[idx];
  v.x = fmaf(v.x, scale[c + 0], shift[c + 0]);
  v.y = fmaf(v.y, scale[c + 1], shift[c + 1]);
  v.z = fmaf(v.z, scale[c + 2], shift[c + 2]);
  v.w = fmaf(v.w, scale[c + 3], shift[c + 3]);
  if (relu) {
    v.x = fmaxf(v.x, 0.f); v.y = fmaxf(v.y, 0.f);
    v.z = fmaxf(v.z, 0.f); v.w = fmaxf(v.w, 0.f);
  }
  ((float4*)out)[idx] = v;
}

// ---------------- pooling / readout / small ops ----------------

__global__ __launch_bounds__(256) void k_pool(const float* __restrict__ X,
                                              const int* __restrict__ batch,
                                              float* __restrict__ pooled, int N) {
  int idx = blockIdx.x * 256 + threadIdx.x;
  if (idx >= N * HDIM) return;
  int n = idx >> 7;
  int c = idx & 127;
  atomicAdd(&pooled[(size_t)batch[n] * HDIM + c], X[idx]);
}

__global__ __launch_bounds__(256) void k_counts(const int* __restrict__ batch,
                                                float* __restrict__ counts, int N) {
  int n = blockIdx.x * 256 + threadIdx.x;
  if (n < N) atomicAdd(&counts[batch[n]], 1.0f);
}

__global__ __launch_bounds__(256) void k_add(const float* __restrict__ a,
                                             const float* __restrict__ b,
                                             float* __restrict__ o, int n) {
  int idx = blockIdx.x * 256 + threadIdx.x;
  if (idx < n) o[idx] = a[idx] + b[idx];
}

__global__ __launch_bounds__(256) void k_readout(const float* __restrict__ pooled,
                                                 const float* __restrict__ counts,
                                                 float* __restrict__ out, int n) {
  int idx = blockIdx.x * 256 + threadIdx.x;
  if (idx >= n) return;
  int g = idx >> 7;
  out[idx] = pooled[idx] / fmaxf(counts[g], 1.0f);
}

// ---------------- launch ----------------

extern "C" void kernel_launch(void* const* d_in, const int* in_sizes, int n_in,
                              void* d_out, int out_size, void* d_ws, size_t ws_size,
                              hipStream_t stream) {
  const float* x       = (const float*)d_in[0];
  const int*   ei      = (const int*)d_in[1];
  const int*   batch   = (const int*)d_in[2];
  const float* conv_w1 = (const float*)d_in[4];
  const float* conv_b1 = (const float*)d_in[5];
  const float* conv_bng = (const float*)d_in[6];
  const float* conv_bnb = (const float*)d_in[7];
  const float* conv_w2 = (const float*)d_in[8];
  const float* conv_b2 = (const float*)d_in[9];
  const float* bn_g    = (const float*)d_in[10];
  const float* bn_b    = (const float*)d_in[11];
  const float* vn_emb  = (const float*)d_in[12];
  const float* vw1     = (const float*)d_in[13];
  const float* vb1     = (const float*)d_in[14];
  const float* vbn1g   = (const float*)d_in[15];
  const float* vbn1b   = (const float*)d_in[16];
  const float* vw2     = (const float*)d_in[17];
  const float* vb2     = (const float*)d_in[18];
  const float* vbn2g   = (const float*)d_in[19];
  const float* vbn2b   = (const float*)d_in[20];

  const int N = in_sizes[2];
  const int E = in_sizes[1] / 2;
  const int L = 3;

  const size_t NH  = (size_t)N * HDIM;
  const size_t NH2 = (size_t)N * H2DIM;

  float* h      = (float*)d_ws;
  float* y1     = h + NH;
  float* sum1   = y1 + NH2;
  float* ss1    = sum1 + H2DIM;
  float* sum2   = ss1 + H2DIM;
  float* ss2    = sum2 + HDIM;
  float* scale1 = ss2 + HDIM;
  float* shift1 = scale1 + H2DIM;
  float* scale2 = shift1 + H2DIM;
  float* shift2 = scale2 + HDIM;
  float* vf     = shift2 + HDIM;
  float* pooled = vf + (size_t)GNUM * HDIM;
  float* vin    = pooled + (size_t)GNUM * HDIM;
  float* v1     = vin + (size_t)GNUM * HDIM;
  float* counts = v1 + (size_t)GNUM * H2DIM;
  int*   cursor = (int*)(counts + GNUM);   // doubles as deg during build
  int*   row_ptr = cursor + N;
  int*   csr    = row_ptr + N + 1;
  int*   bsum   = csr + E;                 // scan block sums (<=256)
  float* y2 = h;

  float* out_feats = (float*)d_out;
  float* out_read  = out_feats + NH;
  float* out_vf    = out_read + (size_t)GNUM * HDIM;
  float* z = out_feats;

  dim3 blk(256);
  const int gridNH4 = (int)((NH / 4 + 255) / 256);
  const int gridE = (E + 255) / 256;
  const int nb = (N + 2047) / 2048;

  // ---- CSR build ----
  hipMemsetAsync(cursor, 0, (size_t)N * sizeof(int), stream);
  k_hist<<<gridE, blk, 0, stream>>>(ei, cursor, E);
  k_scan1<<<nb, blk, 0, stream>>>(cursor, bsum, N);
  k_scan2<<<1, blk, 0, stream>>>(bsum, nb, row_ptr, N);
  k_scan3<<<nb, blk, 0, stream>>>(cursor, bsum, row_ptr, cursor, N);
  k_fill<<<gridE, blk, 0, stream>>>(ei, cursor, csr, E);

  k_init_vf<<<(GNUM * HDIM + 255) / 256, blk, 0, stream>>>(vn_emb, vf);

  for (int i = 0; i < L; ++i) {
    const float* fin = (i == 0) ? x : out_feats;
    k_h_init<<<gridNH4, blk, 0, stream>>>(fin, vf, batch, h, N, i > 0 ? 1 : 0);

    k_aggregate<<<(N + 3) / 4, blk, 0, stream>>>(h, row_ptr, csr, z, N);

    // GEMM1: y1 = z @ W1[i] + b1[i]
    hipMemsetAsync(sum1, 0, (size_t)(H2DIM * 2) * sizeof(float), stream);
    k_gemm128<<<dim3((N + 127) / 128, H2DIM / 128), blk, 0, stream>>>(
        z, conv_w1 + (size_t)i * HDIM * H2DIM, conv_b1 + (size_t)i * H2DIM,
        nullptr, nullptr, y1, N, HDIM, H2DIM);
    k_colstats<<<(N + 127) / 128, H2DIM, 0, stream>>>(y1, N, H2DIM, 128, sum1, ss1);
    k_bnfin<<<1, H2DIM, 0, stream>>>(sum1, ss1, conv_bng + (size_t)i * H2DIM,
                                     conv_bnb + (size_t)i * H2DIM,
                                     scale1, shift1, H2DIM, 1.0f / N);

    // GEMM2: y2 = relu(bn(y1)) @ W2[i] + b2[i]
    hipMemsetAsync(sum2, 0, (size_t)(HDIM * 2) * sizeof(float), stream);
    k_gemm128<<<dim3((N + 127) / 128, HDIM / 128), blk, 0, stream>>>(
        y1, conv_w2 + (size_t)i * H2DIM * HDIM, conv_b2 + (size_t)i * HDIM,
        scale1, shift1, y2, N, H2DIM, HDIM);
    k_colstats<<<(N + 127) / 128, HDIM, 0, stream>>>(y2, N, HDIM, 128, sum2, ss2);
    k_bnfin<<<1, HDIM, 0, stream>>>(sum2, ss2, bn_g + (size_t)i * HDIM,
                                    bn_b + (size_t)i * HDIM,
                                    scale2, shift2, HDIM, 1.0f / N);
    k_bnapply<<<gridNH4, blk, 0, stream>>>(y2, scale2, shift2, out_feats,
                                           (long long)(NH / 4), HDIM / 4,
                                           (i < L - 1) ? 1 : 0);

    if (i == 1) {
      hipMemsetAsync(pooled, 0, (size_t)GNUM * HDIM * sizeof(float), stream);
      k_pool<<<(int)((NH + 255) / 256), blk, 0, stream>>>(out_feats, batch, pooled, N);
      k_add<<<(GNUM * HDIM + 255) / 256, blk, 0, stream>>>(pooled, vf, vin, GNUM * HDIM);

      hipMemsetAsync(sum1, 0, (size_t)(H2DIM * 2) * sizeof(float), stream);
      k_gemm<<<dim3(GNUM / 64, H2DIM / 64), blk, 0, stream>>>(
          vin, vw1, vb1, nullptr, nullptr, v1, GNUM, HDIM, H2DIM);
      k_colstats<<<(GNUM + 127) / 128, H2DIM, 0, stream>>>(v1, GNUM, H2DIM, 128, sum1, ss1);
      k_bnfin<<<1, H2DIM, 0, stream>>>(sum1, ss1, vbn1g, vbn1b, scale1, shift1,
                                       H2DIM, 1.0f / GNUM);

      hipMemsetAsync(sum2, 0, (size_t)(HDIM * 2) * sizeof(float), stream);
      k_gemm<<<dim3(GNUM / 64, HDIM / 64), blk, 0, stream>>>(
          v1, vw2, vb2, scale1, shift1, vin, GNUM, H2DIM, HDIM);
      k_colstats<<<(GNUM + 127) / 128, HDIM, 0, stream>>>(vin, GNUM, HDIM, 128, sum2, ss2);
      k_bnfin<<<1, HDIM, 0, stream>>>(sum2, ss2, vbn2g, vbn2b, scale2, shift2,
                                      HDIM, 1.0f / GNUM);
      k_bnapply<<<(GNUM * HDIM / 4 + 255) / 256, blk, 0, stream>>>(
          vin, scale2, shift2, vf, (long long)(GNUM * HDIM / 4), HDIM / 4, 1);
    }
  }

  hipMemsetAsync(pooled, 0, (size_t)GNUM * HDIM * sizeof(float), stream);
  hipMemsetAsync(counts, 0, (size_t)GNUM * sizeof(float), stream);
  k_pool<<<(int)((NH + 255) / 256), blk, 0, stream>>>(out_feats, batch, pooled, N);
  k_counts<<<(N + 255) / 256, blk, 0, stream>>>(batch, counts, N);
  k_readout<<<(GNUM * HDIM + 255) / 256, blk, 0, stream>>>(pooled, counts, out_read,
                                                           GNUM * HDIM);
  hipMemcpyAsync(out_vf, vf, (size_t)GNUM * HDIM * sizeof(float),
                 hipMemcpyDeviceToDevice, stream);
}

// Round 4
// 1252.583 us; speedup vs baseline: 7.7398x; 1.4901x over previous
//
#include <hip/hip_runtime.h>

// GIN encoder w/ virtual node, 3 layers, H=128. Round 4:
// bf16 MFMA GEMMs (fused bias+colstats+BN-on-load) + bf16 aggregation.

#define HDIM 128
#define H2DIM 256
#define GNUM 512
#define BN_EPS 1e-5f

typedef short bf16x8 __attribute__((ext_vector_type(8)));
typedef float f32x4 __attribute__((ext_vector_type(4)));

__device__ __forceinline__ unsigned short f2bf(float f) {
  unsigned int u = __float_as_uint(f);
  u = (u + 0x7FFFu + ((u >> 16) & 1u)) >> 16;
  return (unsigned short)u;
}
__device__ __forceinline__ float bf2f(unsigned short s) {
  return __uint_as_float(((unsigned int)s) << 16);
}

// ---------------- elementwise / init ----------------

__global__ __launch_bounds__(256) void k_init_vf(const float* __restrict__ emb,
                                                 float* __restrict__ vf) {
  int idx = blockIdx.x * 256 + threadIdx.x;
  if (idx < GNUM * HDIM) vf[idx] = emb[idx & (HDIM - 1)];
}

// h(bf16) = feats (+ vf[batch])
__global__ __launch_bounds__(256) void k_h_init(const float* __restrict__ feats,
                                                const float* __restrict__ vf,
                                                const int* __restrict__ batch,
                                                unsigned short* __restrict__ h,
                                                int N, int useVf) {
  int idx = blockIdx.x * 256 + threadIdx.x;
  int total = N * (HDIM / 4);
  if (idx >= total) return;
  int n = idx >> 5;
  int c4 = idx & 31;
  float4 v = ((const float4*)feats)[idx];
  if (useVf) {
    int g = batch[n];
    float4 w = ((const float4*)(vf + (size_t)g * HDIM))[c4];
    v.x += w.x; v.y += w.y; v.z += w.z; v.w += w.w;
  }
  ushort4 o;
  o.x = f2bf(v.x); o.y = f2bf(v.y); o.z = f2bf(v.z); o.w = f2bf(v.w);
  ((ushort4*)h)[idx] = o;
}

// weight transpose + bf16: w [K][Nc] f32 -> wt [Nc][K] bf16
__global__ __launch_bounds__(256) void k_convw(const float* __restrict__ w,
                                               unsigned short* __restrict__ wt,
                                               int K, int Nc) {
  int o = blockIdx.x * 256 + threadIdx.x;
  if (o >= K * Nc) return;
  int n = o / K, k = o % K;
  wt[o] = f2bf(w[(size_t)k * Nc + n]);
}

// ---------------- CSR build ----------------

__global__ __launch_bounds__(256) void k_hist(const int* __restrict__ ei,
                                              int* __restrict__ deg, int E) {
  int e = blockIdx.x * 256 + threadIdx.x;
  if (e < E) atomicAdd(&deg[ei[E + e]], 1);
}

__global__ __launch_bounds__(256) void k_scan1(const int* __restrict__ deg,
                                               int* __restrict__ bsum, int N) {
  __shared__ int sh[256];
  int t = threadIdx.x;
  int base = blockIdx.x * 2048 + t * 8;
  int s = 0;
#pragma unroll
  for (int j = 0; j < 8; ++j) {
    int i = base + j;
    if (i < N) s += deg[i];
  }
  sh[t] = s;
  __syncthreads();
  for (int off = 128; off > 0; off >>= 1) {
    if (t < off) sh[t] += sh[t + off];
    __syncthreads();
  }
  if (t == 0) bsum[blockIdx.x] = sh[0];
}

__global__ __launch_bounds__(256) void k_scan2(int* __restrict__ bsum, int nb,
                                               int* __restrict__ row_ptr, int N) {
  __shared__ int sh[256];
  int t = threadIdx.x;
  int v = (t < nb) ? bsum[t] : 0;
  sh[t] = v;
  __syncthreads();
  for (int off = 1; off < 256; off <<= 1) {
    int add = (t >= off) ? sh[t - off] : 0;
    __syncthreads();
    sh[t] += add;
    __syncthreads();
  }
  if (t < nb) bsum[t] = sh[t] - v;
  if (t == 255) row_ptr[N] = sh[255];
}

__global__ __launch_bounds__(256) void k_scan3(const int* __restrict__ deg,
                                               const int* __restrict__ boff,
                                               int* __restrict__ row_ptr,
                                               int* __restrict__ cursor, int N) {
  __shared__ int sh[256];
  int t = threadIdx.x;
  int base = blockIdx.x * 2048 + t * 8;
  int d[8];
  int s = 0;
#pragma unroll
  for (int j = 0; j < 8; ++j) {
    int i = base + j;
    d[j] = (i < N) ? deg[i] : 0;
    s += d[j];
  }
  sh[t] = s;
  __syncthreads();
  for (int off = 1; off < 256; off <<= 1) {
    int add = (t >= off) ? sh[t - off] : 0;
    __syncthreads();
    sh[t] += add;
    __syncthreads();
  }
  int run = boff[blockIdx.x] + sh[t] - s;
#pragma unroll
  for (int j = 0; j < 8; ++j) {
    int i = base + j;
    if (i < N) {
      row_ptr[i] = run;
      cursor[i] = run;
      run += d[j];
    }
  }
}

__global__ __launch_bounds__(256) void k_fill(const int* __restrict__ ei,
                                              int* __restrict__ cursor,
                                              int* __restrict__ csr, int E) {
  int e = blockIdx.x * 256 + threadIdx.x;
  if (e >= E) return;
  int d = ei[E + e];
  int pos = atomicAdd(&cursor[d], 1);
  csr[pos] = ei[e];
}

// ---------------- aggregation (bf16): z[n] = h[n] + sum_{s in N(n)} h[s] -------
__global__ __launch_bounds__(256) void k_aggregate(const unsigned short* __restrict__ h,
                                                   const int* __restrict__ row_ptr,
                                                   const int* __restrict__ csr,
                                                   unsigned short* __restrict__ z,
                                                   int N) {
  int n = blockIdx.x * 4 + (threadIdx.x >> 6);
  if (n >= N) return;
  int lane = threadIdx.x & 63;
  const unsigned int* __restrict__ hp = (const unsigned int*)h;
  unsigned int u = hp[(size_t)n * 64 + lane];
  float ax = bf2f((unsigned short)u);
  float ay = bf2f((unsigned short)(u >> 16));
  int beg = row_ptr[n], end = row_ptr[n + 1];
  int j = beg;
  for (; j + 4 <= end; j += 4) {
    int s0 = csr[j + 0], s1 = csr[j + 1], s2 = csr[j + 2], s3 = csr[j + 3];
    unsigned int u0 = hp[(size_t)s0 * 64 + lane];
    unsigned int u1 = hp[(size_t)s1 * 64 + lane];
    unsigned int u2 = hp[(size_t)s2 * 64 + lane];
    unsigned int u3 = hp[(size_t)s3 * 64 + lane];
    ax += bf2f((unsigned short)u0) + bf2f((unsigned short)u1) +
          bf2f((unsigned short)u2) + bf2f((unsigned short)u3);
    ay += bf2f((unsigned short)(u0 >> 16)) + bf2f((unsigned short)(u1 >> 16)) +
          bf2f((unsigned short)(u2 >> 16)) + bf2f((unsigned short)(u3 >> 16));
  }
  for (; j < end; ++j) {
    unsigned int uu = hp[(size_t)csr[j] * 64 + lane];
    ax += bf2f((unsigned short)uu);
    ay += bf2f((unsigned short)(uu >> 16));
  }
  ((unsigned int*)z)[(size_t)n * 64 + lane] =
      (unsigned int)f2bf(ax) | ((unsigned int)f2bf(ay) << 16);
}

// ---------------- MFMA GEMM: C = act(A) @ Wt^T + bias, fused column stats -----
// A [M][K] bf16 row-major; Wt [Nc][K] bf16 row-major (B transposed).
// Optional per-k BN+ReLU on A load (kscale/kshift, f32). Output f32 or bf16.
// Stats: sum/sumsq per column (incl bias) atomically accumulated.
__global__ __launch_bounds__(256) void k_gemm_mfma(
    const unsigned short* __restrict__ A, const unsigned short* __restrict__ Wt,
    const float* __restrict__ bias, const float* __restrict__ kscale,
    const float* __restrict__ kshift, void* __restrict__ Cout, int outBf16,
    float* __restrict__ sumc, float* __restrict__ ssc, int M, int K, int Nc) {
  // padded rows: 136 shorts (17 granules of 16B) to avoid bank conflicts
  __shared__ unsigned short As[128 * 136];
  __shared__ unsigned short Bs[128 * 136];
  __shared__ float redS[128];
  __shared__ float redQ[128];

  int tid = threadIdx.x;
  int lane = tid & 63;
  int wid = tid >> 6;
  int wrow = (wid & 1) * 64;
  int wcol = (wid >> 1) * 64;
  int bm = blockIdx.x * 128;
  int bn = blockIdx.y * 128;

  if (tid < 128) { redS[tid] = 0.f; redQ[tid] = 0.f; }

  f32x4 acc[4][4];
#pragma unroll
  for (int r = 0; r < 4; ++r)
#pragma unroll
    for (int c = 0; c < 4; ++c) acc[r][c] = (f32x4){0.f, 0.f, 0.f, 0.f};

  for (int kt = 0; kt < K; kt += 128) {
    __syncthreads();
    // stage A and Wt tiles: 128 rows x 128 k (bf16), 16B granules
#pragma unroll
    for (int it = 0; it < 8; ++it) {
      int gid = it * 256 + tid;      // 0..2047
      int row = gid >> 4;
      int g = gid & 15;
      int k0 = kt + g * 8;
      // A
      bf16x8 av = (bf16x8){0, 0, 0, 0, 0, 0, 0, 0};
      int grow = bm + row;
      if (grow < M) av = *(const bf16x8*)(A + (size_t)grow * K + k0);
      if (kscale) {
#pragma unroll
        for (int j = 0; j < 8; ++j) {
          float f = bf2f((unsigned short)av[j]);
          f = fmaxf(fmaf(f, kscale[k0 + j], kshift[k0 + j]), 0.f);
          av[j] = (short)f2bf(f);
        }
      }
      *(bf16x8*)(As + row * 136 + g * 8) = av;
      // Wt (Nc is a multiple of 128 -> no guard)
      bf16x8 bv = *(const bf16x8*)(Wt + (size_t)(bn + row) * K + k0);
      *(bf16x8*)(Bs + row * 136 + g * 8) = bv;
    }
    __syncthreads();
#pragma unroll
    for (int kb = 0; kb < 4; ++kb) {
      int lrow = lane & 15;
      int goff = kb * 4 + (lane >> 4);
      bf16x8 af[4], bfr[4];
#pragma unroll
      for (int rf = 0; rf < 4; ++rf)
        af[rf] = *(const bf16x8*)(As + (wrow + rf * 16 + lrow) * 136 + goff * 8);
#pragma unroll
      for (int cf = 0; cf < 4; ++cf)
        bfr[cf] = *(const bf16x8*)(Bs + (wcol + cf * 16 + lrow) * 136 + goff * 8);
#pragma unroll
      for (int rf = 0; rf < 4; ++rf)
#pragma unroll
        for (int cf = 0; cf < 4; ++cf)
          acc[rf][cf] = __builtin_amdgcn_mfma_f32_16x16x32_bf16(
              af[rf], bfr[cf], acc[rf][cf], 0, 0, 0);
    }
  }
  __syncthreads();

  // epilogue: bias + store + column stats
#pragma unroll
  for (int cf = 0; cf < 4; ++cf) {
    int lcol = wcol + cf * 16 + (lane & 15);
    int col = bn + lcol;
    float bb = bias[col];
    float s = 0.f, q = 0.f;
#pragma unroll
    for (int rf = 0; rf < 4; ++rf) {
#pragma unroll
      for (int j = 0; j < 4; ++j) {
        int grow = bm + wrow + rf * 16 + (lane >> 4) * 4 + j;
        if (grow < M) {
          float v = acc[rf][cf][j] + bb;
          s += v; q += v * v;
          if (outBf16)
            ((unsigned short*)Cout)[(size_t)grow * Nc + col] = f2bf(v);
          else
            ((float*)Cout)[(size_t)grow * Nc + col] = v;
        }
      }
    }
    s += __shfl_xor(s, 16); s += __shfl_xor(s, 32);
    q += __shfl_xor(q, 16); q += __shfl_xor(q, 32);
    if (lane < 16) {
      atomicAdd(&redS[lcol], s);
      atomicAdd(&redQ[lcol], q);
    }
  }
  __syncthreads();
  if (tid < 128) {
    atomicAdd(&sumc[bn + tid], redS[tid]);
    atomicAdd(&ssc[bn + tid], redQ[tid]);
  }
}

// ---------------- GEMM 64x64 f32 (vn-MLP, 512 rows) ----------------
__global__ __launch_bounds__(256) void k_gemm(const float* __restrict__ A,
                                              const float* __restrict__ B,
                                              const float* __restrict__ bias,
                                              const float* __restrict__ kscale,
                                              const float* __restrict__ kshift,
                                              float* __restrict__ C,
                                              int M, int K, int Nc) {
  __shared__ float As[16][65];
  __shared__ float Bs[16][65];
  int tid = threadIdx.x;
  int bm = blockIdx.x * 64;
  int bn = blockIdx.y * 64;
  int trow = (tid >> 4) << 2;
  int tcol = (tid & 15) << 2;
  float acc[4][4] = {};

  int arow = tid >> 2;
  int ak = (tid & 3) << 2;
  int bt4 = tid << 2;
  int bk = bt4 >> 6;
  int bcol = bt4 & 63;

  for (int kt = 0; kt < K; kt += 16) {
    float4 av = make_float4(0.f, 0.f, 0.f, 0.f);
    int grow = bm + arow;
    if (grow < M) av = *(const float4*)(A + (size_t)grow * K + kt + ak);
    if (kscale) {
      int k0 = kt + ak;
      av.x = fmaxf(fmaf(av.x, kscale[k0 + 0], kshift[k0 + 0]), 0.f);
      av.y = fmaxf(fmaf(av.y, kscale[k0 + 1], kshift[k0 + 1]), 0.f);
      av.z = fmaxf(fmaf(av.z, kscale[k0 + 2], kshift[k0 + 2]), 0.f);
      av.w = fmaxf(fmaf(av.w, kscale[k0 + 3], kshift[k0 + 3]), 0.f);
    }
    float4 bv = *(const float4*)(B + (size_t)(kt + bk) * Nc + bn + bcol);
    __syncthreads();
    As[ak + 0][arow] = av.x;
    As[ak + 1][arow] = av.y;
    As[ak + 2][arow] = av.z;
    As[ak + 3][arow] = av.w;
    Bs[bk][bcol + 0] = bv.x;
    Bs[bk][bcol + 1] = bv.y;
    Bs[bk][bcol + 2] = bv.z;
    Bs[bk][bcol + 3] = bv.w;
    __syncthreads();
#pragma unroll
    for (int k = 0; k < 16; ++k) {
      float a0 = As[k][trow + 0], a1 = As[k][trow + 1];
      float a2 = As[k][trow + 2], a3 = As[k][trow + 3];
      float b0 = Bs[k][tcol + 0], b1 = Bs[k][tcol + 1];
      float b2 = Bs[k][tcol + 2], b3 = Bs[k][tcol + 3];
      acc[0][0] = fmaf(a0, b0, acc[0][0]); acc[0][1] = fmaf(a0, b1, acc[0][1]);
      acc[0][2] = fmaf(a0, b2, acc[0][2]); acc[0][3] = fmaf(a0, b3, acc[0][3]);
      acc[1][0] = fmaf(a1, b0, acc[1][0]); acc[1][1] = fmaf(a1, b1, acc[1][1]);
      acc[1][2] = fmaf(a1, b2, acc[1][2]); acc[1][3] = fmaf(a1, b3, acc[1][3]);
      acc[2][0] = fmaf(a2, b0, acc[2][0]); acc[2][1] = fmaf(a2, b1, acc[2][1]);
      acc[2][2] = fmaf(a2, b2, acc[2][2]); acc[2][3] = fmaf(a2, b3, acc[2][3]);
      acc[3][0] = fmaf(a3, b0, acc[3][0]); acc[3][1] = fmaf(a3, b1, acc[3][1]);
      acc[3][2] = fmaf(a3, b2, acc[3][2]); acc[3][3] = fmaf(a3, b3, acc[3][3]);
    }
  }
#pragma unroll
  for (int r = 0; r < 4; ++r) {
    int grow = bm + trow + r;
    if (grow < M) {
      float4 o;
      o.x = acc[r][0] + bias[bn + tcol + 0];
      o.y = acc[r][1] + bias[bn + tcol + 1];
      o.z = acc[r][2] + bias[bn + tcol + 2];
      o.w = acc[r][3] + bias[bn + tcol + 3];
      *(float4*)(C + (size_t)grow * Nc + bn + tcol) = o;
    }
  }
}

// ---------------- BN stats / finalize / apply ----------------

__global__ void k_colstats(const float* __restrict__ Y, int M, int C, int stripe,
                           float* __restrict__ sum, float* __restrict__ sumsq) {
  int c = threadIdx.x;
  int r0 = blockIdx.x * stripe;
  int r1 = min(r0 + stripe, M);
  float s = 0.f, ss = 0.f;
  for (int r = r0; r < r1; ++r) {
    float v = Y[(size_t)r * C + c];
    s += v; ss += v * v;
  }
  atomicAdd(&sum[c], s);
  atomicAdd(&sumsq[c], ss);
}

__global__ void k_bnfin(const float* __restrict__ sum, const float* __restrict__ sumsq,
                        const float* __restrict__ g, const float* __restrict__ b,
                        float* __restrict__ scale, float* __restrict__ shift,
                        int C, float invM) {
  int c = threadIdx.x;
  if (c >= C) return;
  float mean = sum[c] * invM;
  float var = sumsq[c] * invM - mean * mean;
  float inv = rsqrtf(var + BN_EPS);
  float sc = g[c] * inv;
  scale[c] = sc;
  shift[c] = fmaf(-mean, sc, b[c]);
}

__global__ __launch_bounds__(256) void k_bnapply(const float* __restrict__ Y,
                                                 const float* __restrict__ scale,
                                                 const float* __restrict__ shift,
                                                 float* __restrict__ out,
                                                 long long total4, int Cq, int relu) {
  long long idx = (long long)blockIdx.x * 256 + threadIdx.x;
  if (idx >= total4) return;
  int c = (int)(idx % Cq) * 4;
  float4 v = ((const float4*)Y)[idx];
  v.x = fmaf(v.x, scale[c + 0], shift[c + 0]);
  v.y = fmaf(v.y, scale[c + 1], shift[c + 1]);
  v.z = fmaf(v.z, scale[c + 2], shift[c + 2]);
  v.w = fmaf(v.w, scale[c + 3], shift[c + 3]);
  if (relu) {
    v.x = fmaxf(v.x, 0.f); v.y = fmaxf(v.y, 0.f);
    v.z = fmaxf(v.z, 0.f); v.w = fmaxf(v.w, 0.f);
  }
  ((float4*)out)[idx] = v;
}

// ---------------- pooling / readout / small ops ----------------

__global__ __launch_bounds__(256) void k_pool(const float* __restrict__ X,
                                              const int* __restrict__ batch,
                                              float* __restrict__ pooled, int N) {
  int idx = blockIdx.x * 256 + threadIdx.x;
  if (idx >= N * HDIM) return;
  int n = idx >> 7;
  int c = idx & 127;
  atomicAdd(&pooled[(size_t)batch[n] * HDIM + c], X[idx]);
}

__global__ __launch_bounds__(256) void k_counts(const int* __restrict__ batch,
                                                float* __restrict__ counts, int N) {
  int n = blockIdx.x * 256 + threadIdx.x;
  if (n < N) atomicAdd(&counts[batch[n]], 1.0f);
}

__global__ __launch_bounds__(256) void k_add(const float* __restrict__ a,
                                             const float* __restrict__ b,
                                             float* __restrict__ o, int n) {
  int idx = blockIdx.x * 256 + threadIdx.x;
  if (idx < n) o[idx] = a[idx] + b[idx];
}

__global__ __launch_bounds__(256) void k_readout(const float* __restrict__ pooled,
                                                 const float* __restrict__ counts,
                                                 float* __restrict__ out, int n) {
  int idx = blockIdx.x * 256 + threadIdx.x;
  if (idx >= n) return;
  int g = idx >> 7;
  out[idx] = pooled[idx] / fmaxf(counts[g], 1.0f);
}

// ---------------- launch ----------------

extern "C" void kernel_launch(void* const* d_in, const int* in_sizes, int n_in,
                              void* d_out, int out_size, void* d_ws, size_t ws_size,
                              hipStream_t stream) {
  const float* x       = (const float*)d_in[0];
  const int*   ei      = (const int*)d_in[1];
  const int*   batch   = (const int*)d_in[2];
  const float* conv_w1 = (const float*)d_in[4];
  const float* conv_b1 = (const float*)d_in[5];
  const float* conv_bng = (const float*)d_in[6];
  const float* conv_bnb = (const float*)d_in[7];
  const float* conv_w2 = (const float*)d_in[8];
  const float* conv_b2 = (const float*)d_in[9];
  const float* bn_g    = (const float*)d_in[10];
  const float* bn_b    = (const float*)d_in[11];
  const float* vn_emb  = (const float*)d_in[12];
  const float* vw1     = (const float*)d_in[13];
  const float* vb1     = (const float*)d_in[14];
  const float* vbn1g   = (const float*)d_in[15];
  const float* vbn1b   = (const float*)d_in[16];
  const float* vw2     = (const float*)d_in[17];
  const float* vb2     = (const float*)d_in[18];
  const float* vbn2g   = (const float*)d_in[19];
  const float* vbn2b   = (const float*)d_in[20];

  const int N = in_sizes[2];
  const int E = in_sizes[1] / 2;
  const int L = 3;

  const size_t NH  = (size_t)N * HDIM;
  const size_t NH2 = (size_t)N * H2DIM;

  // workspace layout (~111 MB):
  // [y2 f32 (NH floats)] aliases [h_b bf16 (NH) | z_b bf16 (NH)]
  float*          y2   = (float*)d_ws;
  unsigned short* h_b  = (unsigned short*)d_ws;
  unsigned short* z_b  = h_b + NH;
  unsigned short* y1_b = z_b + NH;                    // NH2 shorts
  unsigned short* wt1b = y1_b + NH2;                  // 3 * H2 * H
  unsigned short* wt2b = wt1b + (size_t)3 * H2DIM * HDIM;  // 3 * H * H2
  float* sum1   = (float*)(wt2b + (size_t)3 * HDIM * H2DIM);
  float* ss1    = sum1 + H2DIM;
  float* sum2   = ss1 + H2DIM;
  float* ss2    = sum2 + HDIM;
  float* scale1 = ss2 + HDIM;
  float* shift1 = scale1 + H2DIM;
  float* scale2 = shift1 + H2DIM;
  float* shift2 = scale2 + HDIM;
  float* vf     = shift2 + HDIM;
  float* pooled = vf + (size_t)GNUM * HDIM;
  float* vin    = pooled + (size_t)GNUM * HDIM;
  float* v1     = vin + (size_t)GNUM * HDIM;
  float* counts = v1 + (size_t)GNUM * H2DIM;
  int*   cursor = (int*)(counts + GNUM);
  int*   row_ptr = cursor + N;
  int*   csr    = row_ptr + N + 1;
  int*   bsum   = csr + E;

  float* out_feats = (float*)d_out;
  float* out_read  = out_feats + NH;
  float* out_vf    = out_read + (size_t)GNUM * HDIM;

  dim3 blk(256);
  const int gridNH4 = (int)((NH / 4 + 255) / 256);
  const int gridE = (E + 255) / 256;
  const int nb = (N + 2047) / 2048;
  const int gridW = (HDIM * H2DIM + 255) / 256;

  // ---- CSR build ----
  hipMemsetAsync(cursor, 0, (size_t)N * sizeof(int), stream);
  k_hist<<<gridE, blk, 0, stream>>>(ei, cursor, E);
  k_scan1<<<nb, blk, 0, stream>>>(cursor, bsum, N);
  k_scan2<<<1, blk, 0, stream>>>(bsum, nb, row_ptr, N);
  k_scan3<<<nb, blk, 0, stream>>>(cursor, bsum, row_ptr, cursor, N);
  k_fill<<<gridE, blk, 0, stream>>>(ei, cursor, csr, E);

  // ---- weight conversion (bf16, transposed) ----
  for (int i = 0; i < L; ++i) {
    k_convw<<<gridW, blk, 0, stream>>>(conv_w1 + (size_t)i * HDIM * H2DIM,
                                       wt1b + (size_t)i * H2DIM * HDIM,
                                       HDIM, H2DIM);
    k_convw<<<gridW, blk, 0, stream>>>(conv_w2 + (size_t)i * H2DIM * HDIM,
                                       wt2b + (size_t)i * HDIM * H2DIM,
                                       H2DIM, HDIM);
  }

  k_init_vf<<<(GNUM * HDIM + 255) / 256, blk, 0, stream>>>(vn_emb, vf);

  for (int i = 0; i < L; ++i) {
    const float* fin = (i == 0) ? x : out_feats;
    k_h_init<<<gridNH4, blk, 0, stream>>>(fin, vf, batch, h_b, N, i > 0 ? 1 : 0);

    k_aggregate<<<(N + 3) / 4, blk, 0, stream>>>(h_b, row_ptr, csr, z_b, N);

    // GEMM1: y1_b(bf16) = z_b @ W1[i] + b1[i], fused stats
    hipMemsetAsync(sum1, 0, (size_t)(H2DIM * 2) * sizeof(float), stream);
    k_gemm_mfma<<<dim3((N + 127) / 128, H2DIM / 128), blk, 0, stream>>>(
        z_b, wt1b + (size_t)i * H2DIM * HDIM, conv_b1 + (size_t)i * H2DIM,
        nullptr, nullptr, y1_b, 1, sum1, ss1, N, HDIM, H2DIM);
    k_bnfin<<<1, H2DIM, 0, stream>>>(sum1, ss1, conv_bng + (size_t)i * H2DIM,
                                     conv_bnb + (size_t)i * H2DIM,
                                     scale1, shift1, H2DIM, 1.0f / N);

    // GEMM2: y2(f32) = relu(bn(y1)) @ W2[i] + b2[i], BN on A-load, fused stats
    hipMemsetAsync(sum2, 0, (size_t)(HDIM * 2) * sizeof(float), stream);
    k_gemm_mfma<<<dim3((N + 127) / 128, HDIM / 128), blk, 0, stream>>>(
        y1_b, wt2b + (size_t)i * HDIM * H2DIM, conv_b2 + (size_t)i * HDIM,
        scale1, shift1, y2, 0, sum2, ss2, N, H2DIM, HDIM);
    k_bnfin<<<1, HDIM, 0, stream>>>(sum2, ss2, bn_g + (size_t)i * HDIM,
                                    bn_b + (size_t)i * HDIM,
                                    scale2, shift2, HDIM, 1.0f / N);
    k_bnapply<<<gridNH4, blk, 0, stream>>>(y2, scale2, shift2, out_feats,
                                           (long long)(NH / 4), HDIM / 4,
                                           (i < L - 1) ? 1 : 0);

    if (i == 1) {  // virtual-node MLP update (f32 path, tiny)
      hipMemsetAsync(pooled, 0, (size_t)GNUM * HDIM * sizeof(float), stream);
      k_pool<<<(int)((NH + 255) / 256), blk, 0, stream>>>(out_feats, batch, pooled, N);
      k_add<<<(GNUM * HDIM + 255) / 256, blk, 0, stream>>>(pooled, vf, vin, GNUM * HDIM);

      hipMemsetAsync(sum1, 0, (size_t)(H2DIM * 2) * sizeof(float), stream);
      k_gemm<<<dim3(GNUM / 64, H2DIM / 64), blk, 0, stream>>>(
          vin, vw1, vb1, nullptr, nullptr, v1, GNUM, HDIM, H2DIM);
      k_colstats<<<(GNUM + 127) / 128, H2DIM, 0, stream>>>(v1, GNUM, H2DIM, 128, sum1, ss1);
      k_bnfin<<<1, H2DIM, 0, stream>>>(sum1, ss1, vbn1g, vbn1b, scale1, shift1,
                                       H2DIM, 1.0f / GNUM);

      hipMemsetAsync(sum2, 0, (size_t)(HDIM * 2) * sizeof(float), stream);
      k_gemm<<<dim3(GNUM / 64, HDIM / 64), blk, 0, stream>>>(
          v1, vw2, vb2, scale1, shift1, vin, GNUM, H2DIM, HDIM);
      k_colstats<<<(GNUM + 127) / 128, HDIM, 0, stream>>>(vin, GNUM, HDIM, 128, sum2, ss2);
      k_bnfin<<<1, HDIM, 0, stream>>>(sum2, ss2, vbn2g, vbn2b, scale2, shift2,
                                      HDIM, 1.0f / GNUM);
      k_bnapply<<<(GNUM * HDIM / 4 + 255) / 256, blk, 0, stream>>>(
          vin, scale2, shift2, vf, (long long)(GNUM * HDIM / 4), HDIM / 4, 1);
    }
  }

  hipMemsetAsync(pooled, 0, (size_t)GNUM * HDIM * sizeof(float), stream);
  hipMemsetAsync(counts, 0, (size_t)GNUM * sizeof(float), stream);
  k_pool<<<(int)((NH + 255) / 256), blk, 0, stream>>>(out_feats, batch, pooled, N);
  k_counts<<<(N + 255) / 256, blk, 0, stream>>>(batch, counts, N);
  k_readout<<<(GNUM * HDIM + 255) / 256, blk, 0, stream>>>(pooled, counts, out_read,
                                                           GNUM * HDIM);
  hipMemcpyAsync(out_vf, vf, (size_t)GNUM * HDIM * sizeof(float),
                 hipMemcpyDeviceToDevice, stream);
}

// Round 5
// 1010.178 us; speedup vs baseline: 9.5970x; 1.2400x over previous
//
#include <hip/hip_runtime.h>

// GIN encoder w/ virtual node, 3 layers, H=128. Round 5:
// binned CSR fill (kills 16x write amplification), fused layer-0 BN epilogue,
// sorted segment pooling. Numeric path identical to round 4.

#define HDIM 128
#define H2DIM 256
#define GNUM 512
#define BN_EPS 1e-5f

typedef short bf16x8 __attribute__((ext_vector_type(8)));
typedef float f32x4 __attribute__((ext_vector_type(4)));

__device__ __forceinline__ unsigned short f2bf(float f) {
  unsigned int u = __float_as_uint(f);
  u = (u + 0x7FFFu + ((u >> 16) & 1u)) >> 16;
  return (unsigned short)u;
}
__device__ __forceinline__ float bf2f(unsigned short s) {
  return __uint_as_float(((unsigned int)s) << 16);
}

// ---------------- elementwise / init ----------------

__global__ __launch_bounds__(256) void k_init_vf(const float* __restrict__ emb,
                                                 float* __restrict__ vf) {
  int idx = blockIdx.x * 256 + threadIdx.x;
  if (idx < GNUM * HDIM) vf[idx] = emb[idx & (HDIM - 1)];
}

// h(bf16) = feats (+ vf[batch])
__global__ __launch_bounds__(256) void k_h_init(const float* __restrict__ feats,
                                                const float* __restrict__ vf,
                                                const int* __restrict__ batch,
                                                unsigned short* __restrict__ h,
                                                int N, int useVf) {
  int idx = blockIdx.x * 256 + threadIdx.x;
  int total = N * (HDIM / 4);
  if (idx >= total) return;
  int n = idx >> 5;
  int c4 = idx & 31;
  float4 v = ((const float4*)feats)[idx];
  if (useVf) {
    int g = batch[n];
    float4 w = ((const float4*)(vf + (size_t)g * HDIM))[c4];
    v.x += w.x; v.y += w.y; v.z += w.z; v.w += w.w;
  }
  ushort4 o;
  o.x = f2bf(v.x); o.y = f2bf(v.y); o.z = f2bf(v.z); o.w = f2bf(v.w);
  ((ushort4*)h)[idx] = o;
}

// fused: h(bf16) = relu(bn(y2)) + vf[batch]   (layer-0 epilogue)
__global__ __launch_bounds__(256) void k_bnfuse(const float* __restrict__ Y,
                                                const float* __restrict__ scale,
                                                const float* __restrict__ shift,
                                                const float* __restrict__ vf,
                                                const int* __restrict__ batch,
                                                unsigned short* __restrict__ hout,
                                                int N) {
  int idx = blockIdx.x * 256 + threadIdx.x;
  int total = N * (HDIM / 4);
  if (idx >= total) return;
  int n = idx >> 5;
  int c4 = idx & 31;
  int c = c4 * 4;
  float4 v = ((const float4*)Y)[idx];
  int g = batch[n];
  float4 w = ((const float4*)(vf + (size_t)g * HDIM))[c4];
  v.x = fmaxf(fmaf(v.x, scale[c + 0], shift[c + 0]), 0.f) + w.x;
  v.y = fmaxf(fmaf(v.y, scale[c + 1], shift[c + 1]), 0.f) + w.y;
  v.z = fmaxf(fmaf(v.z, scale[c + 2], shift[c + 2]), 0.f) + w.z;
  v.w = fmaxf(fmaf(v.w, scale[c + 3], shift[c + 3]), 0.f) + w.w;
  ushort4 o;
  o.x = f2bf(v.x); o.y = f2bf(v.y); o.z = f2bf(v.z); o.w = f2bf(v.w);
  ((ushort4*)hout)[idx] = o;
}

// fused weight transpose+bf16 for all 6 conv weights
__global__ __launch_bounds__(256) void k_convw_all(const float* __restrict__ w1,
                                                   const float* __restrict__ w2,
                                                   unsigned short* __restrict__ wt1,
                                                   unsigned short* __restrict__ wt2) {
  int idx = blockIdx.x * 256 + threadIdx.x;
  const int P = 3 * HDIM * H2DIM;
  if (idx < P) {
    int i = idx / (H2DIM * HDIM);
    int o = idx % (H2DIM * HDIM);
    int n = o / HDIM;   // Nc = H2
    int k = o % HDIM;   // K  = H
    wt1[idx] = f2bf(w1[(size_t)i * HDIM * H2DIM + (size_t)k * H2DIM + n]);
  } else if (idx < 2 * P) {
    int o2 = idx - P;
    int i = o2 / (HDIM * H2DIM);
    int o = o2 % (HDIM * H2DIM);
    int n = o / H2DIM;  // Nc = H
    int k = o % H2DIM;  // K  = H2
    wt2[o2] = f2bf(w2[(size_t)i * H2DIM * HDIM + (size_t)k * HDIM + n]);
  }
}

// ---------------- CSR build ----------------

__global__ __launch_bounds__(256) void k_hist(const int* __restrict__ ei,
                                              int* __restrict__ deg, int E) {
  int e = blockIdx.x * 256 + threadIdx.x;
  if (e < E) atomicAdd(&deg[ei[E + e]], 1);
}

__global__ __launch_bounds__(256) void k_scan1(const int* __restrict__ deg,
                                               int* __restrict__ bsum, int N) {
  __shared__ int sh[256];
  int t = threadIdx.x;
  int base = blockIdx.x * 2048 + t * 8;
  int s = 0;
#pragma unroll
  for (int j = 0; j < 8; ++j) {
    int i = base + j;
    if (i < N) s += deg[i];
  }
  sh[t] = s;
  __syncthreads();
  for (int off = 128; off > 0; off >>= 1) {
    if (t < off) sh[t] += sh[t + off];
    __syncthreads();
  }
  if (t == 0) bsum[blockIdx.x] = sh[0];
}

__global__ __launch_bounds__(256) void k_scan2(int* __restrict__ bsum, int nb,
                                               int* __restrict__ row_ptr, int N) {
  __shared__ int sh[256];
  int t = threadIdx.x;
  int v = (t < nb) ? bsum[t] : 0;
  sh[t] = v;
  __syncthreads();
  for (int off = 1; off < 256; off <<= 1) {
    int add = (t >= off) ? sh[t - off] : 0;
    __syncthreads();
    sh[t] += add;
    __syncthreads();
  }
  if (t < nb) bsum[t] = sh[t] - v;
  if (t == 255) row_ptr[N] = sh[255];
}

__global__ __launch_bounds__(256) void k_scan3(const int* __restrict__ deg,
                                               const int* __restrict__ boff,
                                               int* __restrict__ row_ptr, int N) {
  __shared__ int sh[256];
  int t = threadIdx.x;
  int base = blockIdx.x * 2048 + t * 8;
  int d[8];
  int s = 0;
#pragma unroll
  for (int j = 0; j < 8; ++j) {
    int i = base + j;
    d[j] = (i < N) ? deg[i] : 0;
    s += d[j];
  }
  sh[t] = s;
  __syncthreads();
  for (int off = 1; off < 256; off <<= 1) {
    int add = (t >= off) ? sh[t - off] : 0;
    __syncthreads();
    sh[t] += add;
    __syncthreads();
  }
  int run = boff[blockIdx.x] + sh[t] - s;
#pragma unroll
  for (int j = 0; j < 8; ++j) {
    int i = base + j;
    if (i < N) {
      row_ptr[i] = run;
      run += d[j];
    }
  }
}

// pass A: bin edges by dst>>8 into staged regions (packed (src<<8)|dst&255)
__global__ __launch_bounds__(256) void k_binA(const int* __restrict__ ei,
                                              const int* __restrict__ row_ptr,
                                              int* __restrict__ bktcur,
                                              int* __restrict__ staged,
                                              int E, int NB) {
  __shared__ int hist[512];
  __shared__ int lbase[512];
  int tid = threadIdx.x;
  hist[tid] = 0; hist[tid + 256] = 0;
  __syncthreads();
  int e0 = blockIdx.x * 4096;
#pragma unroll
  for (int j = 0; j < 16; ++j) {
    int e = e0 + j * 256 + tid;
    if (e < E) atomicAdd(&hist[ei[E + e] >> 8], 1);
  }
  __syncthreads();
  for (int t = tid; t < NB; t += 256) {
    int cgot = hist[t];
    if (cgot > 0) lbase[t] = row_ptr[t << 8] + atomicAdd(&bktcur[t], cgot);
    hist[t] = 0;
  }
  __syncthreads();
#pragma unroll
  for (int j = 0; j < 16; ++j) {
    int e = e0 + j * 256 + tid;
    if (e < E) {
      int d = ei[E + e];
      int b = d >> 8;
      int loc = atomicAdd(&hist[b], 1);
      staged[lbase[b] + loc] = (ei[e] << 8) | (d & 255);
    }
  }
}

// pass B: one block per bucket; scatter within private 16KB csr window
__global__ __launch_bounds__(256) void k_binB(const int* __restrict__ row_ptr,
                                              const int* __restrict__ staged,
                                              int* __restrict__ csr, int N) {
  __shared__ int lcur[256];
  int b = blockIdx.x;
  int node0 = b << 8;
  int tid = threadIdx.x;
  int nend = min(node0 + 256, N);
  lcur[tid] = (node0 + tid < N) ? row_ptr[node0 + tid] : 0;
  __syncthreads();
  int s0 = row_ptr[node0];
  int s1 = row_ptr[nend];
  for (int j = s0 + tid; j < s1; j += 256) {
    int rec = staged[j];
    int pos = atomicAdd(&lcur[rec & 255], 1);
    csr[pos] = rec >> 8;
  }
}

// ---------------- aggregation (bf16): z[n] = h[n] + sum_{s in N(n)} h[s] -------
__global__ __launch_bounds__(256) void k_aggregate(const unsigned short* __restrict__ h,
                                                   const int* __restrict__ row_ptr,
                                                   const int* __restrict__ csr,
                                                   unsigned short* __restrict__ z,
                                                   int N) {
  int n = blockIdx.x * 4 + (threadIdx.x >> 6);
  if (n >= N) return;
  int lane = threadIdx.x & 63;
  const unsigned int* __restrict__ hp = (const unsigned int*)h;
  unsigned int u = hp[(size_t)n * 64 + lane];
  float ax = bf2f((unsigned short)u);
  float ay = bf2f((unsigned short)(u >> 16));
  int beg = row_ptr[n], end = row_ptr[n + 1];
  int j = beg;
  for (; j + 4 <= end; j += 4) {
    int s0 = csr[j + 0], s1 = csr[j + 1], s2 = csr[j + 2], s3 = csr[j + 3];
    unsigned int u0 = hp[(size_t)s0 * 64 + lane];
    unsigned int u1 = hp[(size_t)s1 * 64 + lane];
    unsigned int u2 = hp[(size_t)s2 * 64 + lane];
    unsigned int u3 = hp[(size_t)s3 * 64 + lane];
    ax += bf2f((unsigned short)u0) + bf2f((unsigned short)u1) +
          bf2f((unsigned short)u2) + bf2f((unsigned short)u3);
    ay += bf2f((unsigned short)(u0 >> 16)) + bf2f((unsigned short)(u1 >> 16)) +
          bf2f((unsigned short)(u2 >> 16)) + bf2f((unsigned short)(u3 >> 16));
  }
  for (; j < end; ++j) {
    unsigned int uu = hp[(size_t)csr[j] * 64 + lane];
    ax += bf2f((unsigned short)uu);
    ay += bf2f((unsigned short)(uu >> 16));
  }
  ((unsigned int*)z)[(size_t)n * 64 + lane] =
      (unsigned int)f2bf(ax) | ((unsigned int)f2bf(ay) << 16);
}

// ---------------- MFMA GEMM: C = act(A) @ Wt^T + bias, fused column stats -----
__global__ __launch_bounds__(256) void k_gemm_mfma(
    const unsigned short* __restrict__ A, const unsigned short* __restrict__ Wt,
    const float* __restrict__ bias, const float* __restrict__ kscale,
    const float* __restrict__ kshift, void* __restrict__ Cout, int outBf16,
    float* __restrict__ sumc, float* __restrict__ ssc, int M, int K, int Nc) {
  __shared__ unsigned short As[128 * 136];
  __shared__ unsigned short Bs[128 * 136];
  __shared__ float redS[128];
  __shared__ float redQ[128];

  int tid = threadIdx.x;
  int lane = tid & 63;
  int wid = tid >> 6;
  int wrow = (wid & 1) * 64;
  int wcol = (wid >> 1) * 64;
  int bm = blockIdx.x * 128;
  int bn = blockIdx.y * 128;

  if (tid < 128) { redS[tid] = 0.f; redQ[tid] = 0.f; }

  f32x4 acc[4][4];
#pragma unroll
  for (int r = 0; r < 4; ++r)
#pragma unroll
    for (int c = 0; c < 4; ++c) acc[r][c] = (f32x4){0.f, 0.f, 0.f, 0.f};

  for (int kt = 0; kt < K; kt += 128) {
    __syncthreads();
#pragma unroll
    for (int it = 0; it < 8; ++it) {
      int gid = it * 256 + tid;
      int row = gid >> 4;
      int g = gid & 15;
      int k0 = kt + g * 8;
      bf16x8 av = (bf16x8){0, 0, 0, 0, 0, 0, 0, 0};
      int grow = bm + row;
      if (grow < M) av = *(const bf16x8*)(A + (size_t)grow * K + k0);
      if (kscale) {
#pragma unroll
        for (int j = 0; j < 8; ++j) {
          float f = bf2f((unsigned short)av[j]);
          f = fmaxf(fmaf(f, kscale[k0 + j], kshift[k0 + j]), 0.f);
          av[j] = (short)f2bf(f);
        }
      }
      *(bf16x8*)(As + row * 136 + g * 8) = av;
      bf16x8 bv = *(const bf16x8*)(Wt + (size_t)(bn + row) * K + k0);
      *(bf16x8*)(Bs + row * 136 + g * 8) = bv;
    }
    __syncthreads();
#pragma unroll
    for (int kb = 0; kb < 4; ++kb) {
      int lrow = lane & 15;
      int goff = kb * 4 + (lane >> 4);
      bf16x8 af[4], bfr[4];
#pragma unroll
      for (int rf = 0; rf < 4; ++rf)
        af[rf] = *(const bf16x8*)(As + (wrow + rf * 16 + lrow) * 136 + goff * 8);
#pragma unroll
      for (int cf = 0; cf < 4; ++cf)
        bfr[cf] = *(const bf16x8*)(Bs + (wcol + cf * 16 + lrow) * 136 + goff * 8);
#pragma unroll
      for (int rf = 0; rf < 4; ++rf)
#pragma unroll
        for (int cf = 0; cf < 4; ++cf)
          acc[rf][cf] = __builtin_amdgcn_mfma_f32_16x16x32_bf16(
              af[rf], bfr[cf], acc[rf][cf], 0, 0, 0);
    }
  }
  __syncthreads();

#pragma unroll
  for (int cf = 0; cf < 4; ++cf) {
    int lcol = wcol + cf * 16 + (lane & 15);
    int col = bn + lcol;
    float bb = bias[col];
    float s = 0.f, q = 0.f;
#pragma unroll
    for (int rf = 0; rf < 4; ++rf) {
#pragma unroll
      for (int j = 0; j < 4; ++j) {
        int grow = bm + wrow + rf * 16 + (lane >> 4) * 4 + j;
        if (grow < M) {
          float v = acc[rf][cf][j] + bb;
          s += v; q += v * v;
          if (outBf16)
            ((unsigned short*)Cout)[(size_t)grow * Nc + col] = f2bf(v);
          else
            ((float*)Cout)[(size_t)grow * Nc + col] = v;
        }
      }
    }
    s += __shfl_xor(s, 16); s += __shfl_xor(s, 32);
    q += __shfl_xor(q, 16); q += __shfl_xor(q, 32);
    if (lane < 16) {
      atomicAdd(&redS[lcol], s);
      atomicAdd(&redQ[lcol], q);
    }
  }
  __syncthreads();
  if (tid < 128) {
    atomicAdd(&sumc[bn + tid], redS[tid]);
    atomicAdd(&ssc[bn + tid], redQ[tid]);
  }
}

// ---------------- GEMM 64x64 f32 (vn-MLP, 512 rows) ----------------
__global__ __launch_bounds__(256) void k_gemm(const float* __restrict__ A,
                                              const float* __restrict__ B,
                                              const float* __restrict__ bias,
                                              const float* __restrict__ kscale,
                                              const float* __restrict__ kshift,
                                              float* __restrict__ C,
                                              int M, int K, int Nc) {
  __shared__ float As[16][65];
  __shared__ float Bs[16][65];
  int tid = threadIdx.x;
  int bm = blockIdx.x * 64;
  int bn = blockIdx.y * 64;
  int trow = (tid >> 4) << 2;
  int tcol = (tid & 15) << 2;
  float acc[4][4] = {};

  int arow = tid >> 2;
  int ak = (tid & 3) << 2;
  int bt4 = tid << 2;
  int bk = bt4 >> 6;
  int bcol = bt4 & 63;

  for (int kt = 0; kt < K; kt += 16) {
    float4 av = make_float4(0.f, 0.f, 0.f, 0.f);
    int grow = bm + arow;
    if (grow < M) av = *(const float4*)(A + (size_t)grow * K + kt + ak);
    if (kscale) {
      int k0 = kt + ak;
      av.x = fmaxf(fmaf(av.x, kscale[k0 + 0], kshift[k0 + 0]), 0.f);
      av.y = fmaxf(fmaf(av.y, kscale[k0 + 1], kshift[k0 + 1]), 0.f);
      av.z = fmaxf(fmaf(av.z, kscale[k0 + 2], kshift[k0 + 2]), 0.f);
      av.w = fmaxf(fmaf(av.w, kscale[k0 + 3], kshift[k0 + 3]), 0.f);
    }
    float4 bv = *(const float4*)(B + (size_t)(kt + bk) * Nc + bn + bcol);
    __syncthreads();
    As[ak + 0][arow] = av.x;
    As[ak + 1][arow] = av.y;
    As[ak + 2][arow] = av.z;
    As[ak + 3][arow] = av.w;
    Bs[bk][bcol + 0] = bv.x;
    Bs[bk][bcol + 1] = bv.y;
    Bs[bk][bcol + 2] = bv.z;
    Bs[bk][bcol + 3] = bv.w;
    __syncthreads();
#pragma unroll
    for (int k = 0; k < 16; ++k) {
      float a0 = As[k][trow + 0], a1 = As[k][trow + 1];
      float a2 = As[k][trow + 2], a3 = As[k][trow + 3];
      float b0 = Bs[k][tcol + 0], b1 = Bs[k][tcol + 1];
      float b2 = Bs[k][tcol + 2], b3 = Bs[k][tcol + 3];
      acc[0][0] = fmaf(a0, b0, acc[0][0]); acc[0][1] = fmaf(a0, b1, acc[0][1]);
      acc[0][2] = fmaf(a0, b2, acc[0][2]); acc[0][3] = fmaf(a0, b3, acc[0][3]);
      acc[1][0] = fmaf(a1, b0, acc[1][0]); acc[1][1] = fmaf(a1, b1, acc[1][1]);
      acc[1][2] = fmaf(a1, b2, acc[1][2]); acc[1][3] = fmaf(a1, b3, acc[1][3]);
      acc[2][0] = fmaf(a2, b0, acc[2][0]); acc[2][1] = fmaf(a2, b1, acc[2][1]);
      acc[2][2] = fmaf(a2, b2, acc[2][2]); acc[2][3] = fmaf(a2, b3, acc[2][3]);
      acc[3][0] = fmaf(a3, b0, acc[3][0]); acc[3][1] = fmaf(a3, b1, acc[3][1]);
      acc[3][2] = fmaf(a3, b2, acc[3][2]); acc[3][3] = fmaf(a3, b3, acc[3][3]);
    }
  }
#pragma unroll
  for (int r = 0; r < 4; ++r) {
    int grow = bm + trow + r;
    if (grow < M) {
      float4 o;
      o.x = acc[r][0] + bias[bn + tcol + 0];
      o.y = acc[r][1] + bias[bn + tcol + 1];
      o.z = acc[r][2] + bias[bn + tcol + 2];
      o.w = acc[r][3] + bias[bn + tcol + 3];
      *(float4*)(C + (size_t)grow * Nc + bn + tcol) = o;
    }
  }
}

// ---------------- BN stats / finalize / apply ----------------

__global__ void k_colstats(const float* __restrict__ Y, int M, int C, int stripe,
                           float* __restrict__ sum, float* __restrict__ sumsq) {
  int c = threadIdx.x;
  int r0 = blockIdx.x * stripe;
  int r1 = min(r0 + stripe, M);
  float s = 0.f, ss = 0.f;
  for (int r = r0; r < r1; ++r) {
    float v = Y[(size_t)r * C + c];
    s += v; ss += v * v;
  }
  atomicAdd(&sum[c], s);
  atomicAdd(&sumsq[c], ss);
}

__global__ void k_bnfin(const float* __restrict__ sum, const float* __restrict__ sumsq,
                        const float* __restrict__ g, const float* __restrict__ b,
                        float* __restrict__ scale, float* __restrict__ shift,
                        int C, float invM) {
  int c = threadIdx.x;
  if (c >= C) return;
  float mean = sum[c] * invM;
  float var = sumsq[c] * invM - mean * mean;
  float inv = rsqrtf(var + BN_EPS);
  float sc = g[c] * inv;
  scale[c] = sc;
  shift[c] = fmaf(-mean, sc, b[c]);
}

__global__ __launch_bounds__(256) void k_bnapply(const float* __restrict__ Y,
                                                 const float* __restrict__ scale,
                                                 const float* __restrict__ shift,
                                                 float* __restrict__ out,
                                                 long long total4, int Cq, int relu) {
  long long idx = (long long)blockIdx.x * 256 + threadIdx.x;
  if (idx >= total4) return;
  int c = (int)(idx % Cq) * 4;
  float4 v = ((const float4*)Y)[idx];
  v.x = fmaf(v.x, scale[c + 0], shift[c + 0]);
  v.y = fmaf(v.y, scale[c + 1], shift[c + 1]);
  v.z = fmaf(v.z, scale[c + 2], shift[c + 2]);
  v.w = fmaf(v.w, scale[c + 3], shift[c + 3]);
  if (relu) {
    v.x = fmaxf(v.x, 0.f); v.y = fmaxf(v.y, 0.f);
    v.z = fmaxf(v.z, 0.f); v.w = fmaxf(v.w, 0.f);
  }
  ((float4*)out)[idx] = v;
}

// ---------------- pooling / readout / small ops ----------------

// segment-sum pooling over sorted batch: per-thread sequential reduce over a
// 64-row strip, flush on graph change. counts fused (col-0 threads).
__global__ __launch_bounds__(256) void k_pool2(const float* __restrict__ X,
                                               const int* __restrict__ batch,
                                               float* __restrict__ pooled,
                                               float* __restrict__ counts, int N) {
  int c = threadIdx.x & 127;
  int half = threadIdx.x >> 7;
  int base = blockIdx.x * 128 + half * 64;
  if (base >= N) return;
  int lim = min(64, N - base);
  int g = batch[base];
  float acc = 0.f, cnt = 0.f;
  for (int r = 0; r < lim; ++r) {
    int bg = batch[base + r];
    if (bg != g) {
      atomicAdd(&pooled[(size_t)g * HDIM + c], acc);
      if (c == 0 && counts) atomicAdd(&counts[g], cnt);
      acc = 0.f; cnt = 0.f; g = bg;
    }
    acc += X[(size_t)(base + r) * HDIM + c];
    cnt += 1.f;
  }
  atomicAdd(&pooled[(size_t)g * HDIM + c], acc);
  if (c == 0 && counts) atomicAdd(&counts[g], cnt);
}

__global__ __launch_bounds__(256) void k_add(const float* __restrict__ a,
                                             const float* __restrict__ b,
                                             float* __restrict__ o, int n) {
  int idx = blockIdx.x * 256 + threadIdx.x;
  if (idx < n) o[idx] = a[idx] + b[idx];
}

__global__ __launch_bounds__(256) void k_readout(const float* __restrict__ pooled,
                                                 const float* __restrict__ counts,
                                                 float* __restrict__ out, int n) {
  int idx = blockIdx.x * 256 + threadIdx.x;
  if (idx >= n) return;
  int g = idx >> 7;
  out[idx] = pooled[idx] / fmaxf(counts[g], 1.0f);
}

// ---------------- launch ----------------

extern "C" void kernel_launch(void* const* d_in, const int* in_sizes, int n_in,
                              void* d_out, int out_size, void* d_ws, size_t ws_size,
                              hipStream_t stream) {
  const float* x       = (const float*)d_in[0];
  const int*   ei      = (const int*)d_in[1];
  const int*   batch   = (const int*)d_in[2];
  const float* conv_w1 = (const float*)d_in[4];
  const float* conv_b1 = (const float*)d_in[5];
  const float* conv_bng = (const float*)d_in[6];
  const float* conv_bnb = (const float*)d_in[7];
  const float* conv_w2 = (const float*)d_in[8];
  const float* conv_b2 = (const float*)d_in[9];
  const float* bn_g    = (const float*)d_in[10];
  const float* bn_b    = (const float*)d_in[11];
  const float* vn_emb  = (const float*)d_in[12];
  const float* vw1     = (const float*)d_in[13];
  const float* vb1     = (const float*)d_in[14];
  const float* vbn1g   = (const float*)d_in[15];
  const float* vbn1b   = (const float*)d_in[16];
  const float* vw2     = (const float*)d_in[17];
  const float* vb2     = (const float*)d_in[18];
  const float* vbn2g   = (const float*)d_in[19];
  const float* vbn2b   = (const float*)d_in[20];

  const int N = in_sizes[2];
  const int E = in_sizes[1] / 2;
  const int L = 3;

  const size_t NH  = (size_t)N * HDIM;
  const size_t NH2 = (size_t)N * H2DIM;

  // workspace layout (~144 MB):
  // [y2 f32 (NH floats)] aliases [h_b bf16 (NH) | z_b bf16 (NH)]
  float*          y2   = (float*)d_ws;
  unsigned short* h_b  = (unsigned short*)d_ws;
  unsigned short* z_b  = h_b + NH;
  unsigned short* y1_b = z_b + NH;                         // NH2 shorts
  unsigned short* wt1b = y1_b + NH2;                       // 3 * H2 * H
  unsigned short* wt2b = wt1b + (size_t)3 * H2DIM * HDIM;  // 3 * H * H2
  float* sum1   = (float*)(wt2b + (size_t)3 * HDIM * H2DIM);
  float* ss1    = sum1 + H2DIM;
  float* sum2   = ss1 + H2DIM;
  float* ss2    = sum2 + HDIM;
  float* scale1 = ss2 + HDIM;
  float* shift1 = scale1 + H2DIM;
  float* scale2 = shift1 + H2DIM;
  float* shift2 = scale2 + HDIM;
  float* vf     = shift2 + HDIM;
  float* pooled = vf + (size_t)GNUM * HDIM;
  float* vin    = pooled + (size_t)GNUM * HDIM;
  float* v1     = vin + (size_t)GNUM * HDIM;
  float* counts = v1 + (size_t)GNUM * H2DIM;
  int*   cursor = (int*)(counts + GNUM);      // deg (N)
  int*   bktcur = cursor + N;                 // 512
  int*   row_ptr = bktcur + 512;              // N+1
  int*   csr    = row_ptr + N + 1;            // E
  int*   staged = csr + E;                    // E
  int*   bsum   = staged + E;                 // 256
  unsigned short* hb2 = (unsigned short*)(bsum + 256);  // NH shorts

  float* out_feats = (float*)d_out;
  float* out_read  = out_feats + NH;
  float* out_vf    = out_read + (size_t)GNUM * HDIM;

  dim3 blk(256);
  const int gridNH4 = (int)((NH / 4 + 255) / 256);
  const int gridE = (E + 255) / 256;
  const int nb = (N + 2047) / 2048;
  const int NB = (N + 255) >> 8;

  // ---- CSR build ----
  hipMemsetAsync(cursor, 0, (size_t)(N + 512) * sizeof(int), stream);
  k_hist<<<gridE, blk, 0, stream>>>(ei, cursor, E);
  k_scan1<<<nb, blk, 0, stream>>>(cursor, bsum, N);
  k_scan2<<<1, blk, 0, stream>>>(bsum, nb, row_ptr, N);
  k_scan3<<<nb, blk, 0, stream>>>(cursor, bsum, row_ptr, N);
  k_binA<<<(E + 4095) / 4096, blk, 0, stream>>>(ei, row_ptr, bktcur, staged, E, NB);
  k_binB<<<NB, blk, 0, stream>>>(row_ptr, staged, csr, N);

  // ---- weight conversion (bf16, transposed), one launch ----
  k_convw_all<<<(2 * 3 * HDIM * H2DIM + 255) / 256, blk, 0, stream>>>(
      conv_w1, conv_w2, wt1b, wt2b);

  k_init_vf<<<(GNUM * HDIM + 255) / 256, blk, 0, stream>>>(vn_emb, vf);

  for (int i = 0; i < L; ++i) {
    if (i == 0)
      k_h_init<<<gridNH4, blk, 0, stream>>>(x, vf, batch, h_b, N, 0);
    else if (i == 2)
      k_h_init<<<gridNH4, blk, 0, stream>>>(out_feats, vf, batch, h_b, N, 1);
    const unsigned short* hcur = (i == 1) ? hb2 : h_b;

    k_aggregate<<<(N + 3) / 4, blk, 0, stream>>>(hcur, row_ptr, csr, z_b, N);

    // zero sum1|ss1|sum2|ss2 in one call (contiguous, 768 floats)
    hipMemsetAsync(sum1, 0, (size_t)(2 * H2DIM + 2 * HDIM) * sizeof(float), stream);

    // GEMM1: y1_b(bf16) = z_b @ W1[i] + b1[i], fused stats
    k_gemm_mfma<<<dim3((N + 127) / 128, H2DIM / 128), blk, 0, stream>>>(
        z_b, wt1b + (size_t)i * H2DIM * HDIM, conv_b1 + (size_t)i * H2DIM,
        nullptr, nullptr, y1_b, 1, sum1, ss1, N, HDIM, H2DIM);
    k_bnfin<<<1, H2DIM, 0, stream>>>(sum1, ss1, conv_bng + (size_t)i * H2DIM,
                                     conv_bnb + (size_t)i * H2DIM,
                                     scale1, shift1, H2DIM, 1.0f / N);

    // GEMM2: y2(f32) = relu(bn(y1)) @ W2[i] + b2[i], BN on A-load, fused stats
    k_gemm_mfma<<<dim3((N + 127) / 128, HDIM / 128), blk, 0, stream>>>(
        y1_b, wt2b + (size_t)i * HDIM * H2DIM, conv_b2 + (size_t)i * HDIM,
        scale1, shift1, y2, 0, sum2, ss2, N, H2DIM, HDIM);
    k_bnfin<<<1, HDIM, 0, stream>>>(sum2, ss2, bn_g + (size_t)i * HDIM,
                                    bn_b + (size_t)i * HDIM,
                                    scale2, shift2, HDIM, 1.0f / N);

    if (i == 0) {
      // fused: h(layer1) = relu(bn(y2)) + vf[batch]; skip f32 feats0 entirely
      k_bnfuse<<<gridNH4, blk, 0, stream>>>(y2, scale2, shift2, vf, batch, hb2, N);
    } else {
      k_bnapply<<<gridNH4, blk, 0, stream>>>(y2, scale2, shift2, out_feats,
                                             (long long)(NH / 4), HDIM / 4,
                                             (i < L - 1) ? 1 : 0);
    }

    if (i == 1) {  // virtual-node MLP update (f32 path, tiny)
      hipMemsetAsync(pooled, 0, (size_t)GNUM * HDIM * sizeof(float), stream);
      k_pool2<<<(N + 127) / 128, blk, 0, stream>>>(out_feats, batch, pooled,
                                                   nullptr, N);
      k_add<<<(GNUM * HDIM + 255) / 256, blk, 0, stream>>>(pooled, vf, vin,
                                                           GNUM * HDIM);

      hipMemsetAsync(sum1, 0, (size_t)(2 * H2DIM + 2 * HDIM) * sizeof(float), stream);
      k_gemm<<<dim3(GNUM / 64, H2DIM / 64), blk, 0, stream>>>(
          vin, vw1, vb1, nullptr, nullptr, v1, GNUM, HDIM, H2DIM);
      k_colstats<<<(GNUM + 127) / 128, H2DIM, 0, stream>>>(v1, GNUM, H2DIM, 128,
                                                           sum1, ss1);
      k_bnfin<<<1, H2DIM, 0, stream>>>(sum1, ss1, vbn1g, vbn1b, scale1, shift1,
                                       H2DIM, 1.0f / GNUM);

      k_gemm<<<dim3(GNUM / 64, HDIM / 64), blk, 0, stream>>>(
          v1, vw2, vb2, scale1, shift1, vin, GNUM, H2DIM, HDIM);
      k_colstats<<<(GNUM + 127) / 128, HDIM, 0, stream>>>(vin, GNUM, HDIM, 128,
                                                          sum2, ss2);
      k_bnfin<<<1, HDIM, 0, stream>>>(sum2, ss2, vbn2g, vbn2b, scale2, shift2,
                                      HDIM, 1.0f / GNUM);
      k_bnapply<<<(GNUM * HDIM / 4 + 255) / 256, blk, 0, stream>>>(
          vin, scale2, shift2, vf, (long long)(GNUM * HDIM / 4), HDIM / 4, 1);
    }
  }

  // readout: mean pool of final feats (counts fused into pool2)
  hipMemsetAsync(pooled, 0, (size_t)GNUM * HDIM * sizeof(float), stream);
  hipMemsetAsync(counts, 0, (size_t)GNUM * sizeof(float), stream);
  k_pool2<<<(N + 127) / 128, blk, 0, stream>>>(out_feats, batch, pooled, counts, N);
  k_readout<<<(GNUM * HDIM + 255) / 256, blk, 0, stream>>>(pooled, counts, out_read,
                                                           GNUM * HDIM);
  hipMemcpyAsync(out_vf, vf, (size_t)GNUM * HDIM * sizeof(float),
                 hipMemcpyDeviceToDevice, stream);
}